// Round 10
// baseline (109.321 us; speedup 1.0000x reference)
//
#include <hip/hip_runtime.h>

typedef unsigned short u16;
typedef unsigned int   u32;
typedef __attribute__((ext_vector_type(8))) short bf16x8;
typedef __attribute__((ext_vector_type(4))) float f32x4;
typedef __attribute__((ext_vector_type(4))) u32   u32x4;
typedef __attribute__((ext_vector_type(2))) u32   u32x2;

#define MFMA(a,b,c) __builtin_amdgcn_mfma_f32_16x16x32_bf16(a,b,c,0,0,0)

// B=4, S=1024, E=1024, H=16, D=64; M = B*S = 4096.

__device__ __forceinline__ u32 cvtpk(float lo, float hi){
  u32 r; asm("v_cvt_pk_bf16_f32 %0, %1, %2" : "=v"(r) : "v"(lo), "v"(hi)); return r;
}
__device__ __forceinline__ u16 f2bf(float f){ return (u16)cvtpk(f,f); }  // RNE, 1 instr
__device__ __forceinline__ bf16x8 cvt8(f32x4 lo, f32x4 hi){
  u32x4 u;
  u.x = cvtpk(lo[0],lo[1]); u.y = cvtpk(lo[2],lo[3]);
  u.z = cvtpk(hi[0],hi[1]); u.w = cvtpk(hi[2],hi[3]);
  return *(bf16x8*)&u;
}

// XOR swizzle for [row][64 bf16] LDS tiles (128B rows). BYTE offset.
__device__ __forceinline__ int swz(int row, int col){
  return (((row<<6) + col)<<1) ^ ((row&7)<<4);
}

// async global->LDS, 16B/lane; LDS dest wave-uniform (HW adds lane*16)
__device__ __forceinline__ void gl16(const void* g, void* l){
  __builtin_amdgcn_global_load_lds(
      (const __attribute__((address_space(1))) u32*)g,
      (__attribute__((address_space(3))) u32*)l, 16, 0, 0);
}

// stage ROWSx64 bf16 tile via global_load_lds; source-side swizzle ^(row&7).
template<int ROWS>
__device__ __forceinline__ void stage_bf16(const u16* g, size_t ldg, char* lds, int wv, int lane){
  #pragma unroll
  for (int i=0;i<ROWS/32;++i){
    const int r0 = wv*(ROWS/4) + (i<<3);
    const int row = r0 + (lane>>3);
    const int c = ((lane&7) ^ (row&7)) << 3;
    gl16(g + (size_t)row*ldg + c, lds + (r0<<7));
  }
}

// reg-staged f32->bf16 tile: load phase (issue early, hold in regs)
template<int ROWS>
__device__ __forceinline__ void cvt_load(const float* g, f32x4* t, int wv, int lane){
  #pragma unroll
  for (int i=0;i<ROWS/32;++i){
    const int row = wv*(ROWS/4) + (i<<3) + (lane>>3);
    const float* s = g + (size_t)row*1024 + ((lane&7)<<3);
    t[2*i]   = *(const f32x4*)s;
    t[2*i+1] = *(const f32x4*)(s+4);
  }
}
// write phase: 1 b128 per slot; bank bits[4:2] = c16^row -> conflict-free
template<int ROWS>
__device__ __forceinline__ void cvt_write(const f32x4* t, char* lds, int wv, int lane){
  #pragma unroll
  for (int i=0;i<ROWS/32;++i){
    const int row = wv*(ROWS/4) + (i<<3) + (lane>>3);
    *(bf16x8*)(lds + swz(row, (lane&7)<<3)) = cvt8(t[2*i], t[2*i+1]);
  }
}

__device__ __forceinline__ bf16x8 frag_bf16(const char* lds, int row, int kcol){
  return *(const bf16x8*)(lds + swz(row,kcol));
}

// ---------------- mask compaction: scat[b][s] = compact slot or -1; cnts[b] ----------------
__global__ __launch_bounds__(256) void mkidx_k(const int* __restrict__ mask,
    int* __restrict__ scat, int* __restrict__ cnts)
{
  const int b = blockIdx.x, tid = threadIdx.x, lane = tid&63, wv = tid>>6;
  __shared__ int wsum[4];
  const int4 m = *(const int4*)(mask + (b<<10) + (tid<<2));
  const int c0 = (m.x!=0)+(m.y!=0)+(m.z!=0)+(m.w!=0);
  int pre = c0;
  #pragma unroll
  for (int i=1;i<64;i<<=1){
    int t = __shfl_up(pre, i);
    if (lane >= i) pre += t;
  }
  if (lane==63) wsum[wv] = pre;
  __syncthreads();
  int base = pre - c0;
  #pragma unroll
  for (int w=0;w<4;++w) if (w<wv) base += wsum[w];
  int p = base;
  int* sb = scat + (b<<10) + (tid<<2);
  sb[0] = m.x ? p++ : -1;
  sb[1] = m.y ? p++ : -1;
  sb[2] = m.z ? p++ : -1;
  sb[3] = m.w ? p++ : -1;
  if (tid==255) cnts[b] = p;
}

// ---------------- weight fp32 -> bf16 (wq|wk|wo contiguous) ----------------
__global__ __launch_bounds__(256) void cvtw_k(const float* __restrict__ wq,
    const float* __restrict__ wk, const float* __restrict__ wo, u16* __restrict__ out)
{
  const size_t i8 = (((size_t)blockIdx.x<<8) + threadIdx.x) << 3;
  const float* src;
  if      (i8 <  1048576u) src = wq + i8;
  else if (i8 <  2097152u) src = wk + (i8 - 1048576u);
  else                     src = wo + (i8 - 2097152u);
  f32x4 lo = *(const f32x4*)src, hi = *(const f32x4*)(src+4);
  *(bf16x8*)(out + i8) = cvt8(lo, hi);
}

// ---------------- GEMM family: C = A @ B^T (+bias), 2-phase dbuf ----------------
// V=0: A=f32 q/k (reg-cvt), B=bf16 Wq/Wk gl_lds, BN=128, out bf16 [4096,1024]
//      z=1 (k) scatters output rows to compact slots via scat (row dropped if masked).
// V=1: A=bf16 Wk gl_lds, B=f32 v (reg-cvt), BN=64, bias[m], out bf16 vt [1024,4096],
//      output cols scattered to compact slots.
// V=2: A=bf16 ctx, B=bf16 Wo (both gl_lds), BN=64, out f32 [4096,1024]
template<int V>
__global__ __launch_bounds__(256,4) void gemm_k(
    const float* __restrict__ Xf0, const float* __restrict__ Xf1,
    const u16* __restrict__ W0, const u16* __restrict__ W1,
    const float* __restrict__ b0, const float* __restrict__ b1,
    u16* __restrict__ o0, u16* __restrict__ o1, float* __restrict__ of,
    const int* __restrict__ scat)
{
  constexpr int BN = (V==0)?128:64;
  constexpr int NT = BN/32;            // n-frags per wave
  constexpr bool AF = (V==0);          // A reg-cvt from f32
  constexpr bool BF = (V==1);          // B reg-cvt from f32
  __shared__ __align__(16) char As[2][16384];    // 128x64 bf16 dbuf
  __shared__ __align__(16) char Bs[2][BN*128];   // BNx64 bf16 dbuf

  const float* Xa=nullptr;   // f32 source (V0: A, V1: B)
  const u16* Aa=nullptr; const u16* Bb=nullptr;
  const float* bias; u16* outb=nullptr;
  const int* sc=nullptr;
  if (V==0){
    const int z = blockIdx.z;
    Xa = z?Xf1:Xf0; Bb = z?W1:W0; bias = z?b1:b0; outb = z?o1:o0;
    sc = z ? scat : nullptr;
  } else if (V==1){ Aa = W0; Xa = Xf0; bias = b0; outb = o0; sc = scat; }
  else            { Aa = W0; Bb = W1; bias = b0; }

  const int m0 = blockIdx.x<<7, n0 = blockIdx.y*BN;
  const int tid = threadIdx.x, lane = tid&63, wv = tid>>6;
  const int wm = wv>>1, wn = wv&1, l15 = lane&15, g4 = lane>>4;

  f32x4 acc[4][NT] = {};
  f32x4 ta[8];   // V0 A-hold
  f32x4 tb[4];   // V1 B-hold

  // prologue: stage tile 0 into buf 0
  if (AF) cvt_load<128>(Xa + (size_t)m0*1024, ta, wv, lane);
  else    stage_bf16<128>(Aa + (size_t)m0*1024, 1024, As[0], wv, lane);
  if (BF) cvt_load<64>(Xa + (size_t)n0*1024, tb, wv, lane);
  else    stage_bf16<BN>(Bb + (size_t)n0*1024, 1024, Bs[0], wv, lane);
  if (AF) cvt_write<128>(ta, As[0], wv, lane);
  if (BF) cvt_write<64>(tb, Bs[0], wv, lane);
  __syncthreads();

  int cb = 0;
  #pragma unroll 1
  for (int kt=0; kt<1024; kt+=64){
    const bool more = (kt < 960);
    if (more){
      if (AF) cvt_load<128>(Xa + (size_t)m0*1024 + kt+64, ta, wv, lane);
      else    stage_bf16<128>(Aa + (size_t)m0*1024 + kt+64, 1024, As[cb^1], wv, lane);
      if (BF) cvt_load<64>(Xa + (size_t)n0*1024 + kt+64, tb, wv, lane);
      else    stage_bf16<BN>(Bb + (size_t)n0*1024 + kt+64, 1024, Bs[cb^1], wv, lane);
    }
    #pragma unroll
    for (int kb=0;kb<64;kb+=32){
      const int kcol = kb + (g4<<3);
      bf16x8 af[4], bf_[NT];
      #pragma unroll
      for (int t=0;t<4;++t)
        af[t] = frag_bf16(As[cb], (wm<<6) + (t<<4) + l15, kcol);
      #pragma unroll
      for (int t=0;t<NT;++t)
        bf_[t] = frag_bf16(Bs[cb], wn*(BN>>1) + (t<<4) + l15, kcol);
      __builtin_amdgcn_s_setprio(1);
      #pragma unroll
      for (int mt=0;mt<4;++mt)
        #pragma unroll
        for (int nt=0;nt<NT;++nt)
          acc[mt][nt] = MFMA(af[mt], bf_[nt], acc[mt][nt]);
      __builtin_amdgcn_s_setprio(0);
    }
    if (more){
      if (AF) cvt_write<128>(ta, As[cb^1], wv, lane);
      if (BF) cvt_write<64>(tb, Bs[cb^1], wv, lane);
    }
    __syncthreads();
    cb ^= 1;
  }

  // epilogue
  f32x4 bmv[4];
  if (V==1){
    #pragma unroll
    for (int mt=0;mt<4;++mt)
      bmv[mt] = *(const f32x4*)(b0 + m0 + (wm<<6) + (mt<<4) + (g4<<2));
  }
  int drow[4][4];     // V0: scattered dest rows (-1 = drop)
  if (V==0){
    #pragma unroll
    for (int mt=0;mt<4;++mt)
      #pragma unroll
      for (int j=0;j<4;++j){
        const int m = m0 + (wm<<6) + (mt<<4) + (g4<<2) + j;
        int d = m;
        if (sc){ const int c = sc[m]; d = (c<0) ? -1 : ((m & ~1023) | c); }
        drow[mt][j] = d;
      }
  }
  int dcol[NT];       // V1: scattered dest cols (-1 = drop)
  if (V==1){
    #pragma unroll
    for (int nt=0;nt<NT;++nt){
      const int col = n0 + wn*(BN>>1) + (nt<<4) + l15;
      const int c = sc[col];
      dcol[nt] = (c<0) ? -1 : ((col & ~1023) | c);
    }
  }

  #pragma unroll
  for (int nt=0;nt<NT;++nt){
    const int col = n0 + wn*(BN>>1) + (nt<<4) + l15;
    const float bvn = (V==1) ? 0.f : bias[col];
    #pragma unroll
    for (int mt=0;mt<4;++mt){
      const int mb = m0 + (wm<<6) + (mt<<4) + (g4<<2);
      f32x4 a = acc[mt][nt];
      #pragma unroll
      for (int j=0;j<4;++j){
        const float val = a[j] + ((V==1) ? bmv[mt][j] : bvn);
        if (V==2)      of[(size_t)(mb+j)*1024 + col] = val;
        else if (V==1){ if (dcol[nt]>=0) outb[(size_t)(mb+j)*4096 + dcol[nt]] = f2bf(val); }
        else           { if (drow[mt][j]>=0) outb[(size_t)drow[mt][j]*1024 + col] = f2bf(val); }
      }
    }
  }
}

// ---------------- flash attention over COMPACTED keys ----------------
// qp bf16 [B*S,E]; kp bf16 [B*S,E] compact rows; vt bf16 [E,B*S] compact cols.
// cnts[b] = number of live keys. Tail slots guarded by -1e30 bias (exp2 -> 0).
// Block: 128 q-rows x (h,b); 4 waves x 32 rows. KV tiles 64, dbuf.
__global__ __launch_bounds__(256) void attn_k(
    const u16* __restrict__ qp, const u16* __restrict__ kp, const u16* __restrict__ vt,
    const int* __restrict__ cnts, u16* __restrict__ ctx)
{
  const int bid = blockIdx.x;
  const int wg  = (bid&7)*64 + (bid>>3);     // XCD-chunked (512 = 8*64, bijective)
  const int qt = wg&7, h = (wg>>3)&15, b = wg>>7;

  __shared__ __align__(16) u16 Qs[128*64];    // 16KB
  __shared__ __align__(16) u16 Ks[2][64*64];  // 16KB
  __shared__ __align__(16) u16 Vs[2][64*64];  // 16KB (rows=d, cols=key)
  __shared__ __align__(16) u16 Ps[4*32*64];   // 16KB per-wave P

  const int tid = threadIdx.x, lane = tid&63, wv = tid>>6;
  const int hc = h<<6, l15 = lane&15;
  const float C2 = 0.18033688011112042f;      // 0.125 * log2(e)

  const int cnt = cnts[b];
  const int ntiles = (cnt + 63) >> 6;

  { // stage Q (128 x 64)
    const u16* Qg = qp + ((size_t)((b<<10) + (qt<<7)))*1024 + hc;
    #pragma unroll
    for (int i=0;i<4;++i){
      const int r0 = (wv<<5) + (i<<3);
      const int row = r0 + (lane>>3);
      const int c = ((lane&7) ^ (row&7)) << 3;
      gl16(Qg + (size_t)row*1024 + c, (char*)Qs + (r0<<7));
    }
  }

  const u16* Kg = kp + ((size_t)(b<<10))*1024 + hc;
  const u16* Vg = vt + ((size_t)hc)*4096 + (b<<10);

  auto stageKV = [&](int kt2, int bi){
    #pragma unroll
    for (int i=0;i<2;++i){
      const int r0 = (wv<<4) + (i<<3);
      const int row = r0 + (lane>>3);
      const int c = ((lane&7) ^ (row&7)) << 3;
      gl16(Kg + (size_t)((kt2<<6) + row)*1024 + c, (char*)Ks[bi] + (r0<<7));
      gl16(Vg + (size_t)row*4096 + (kt2<<6) + c,  (char*)Vs[bi] + (r0<<7));
    }
  };
  stageKV(0, 0);
  __syncthreads();

  f32x4 o[2][4] = {};
  float lr[2][4] = {};
  u16* Pw = Ps + (wv<<11);
  int cur = 0;

  #pragma unroll 1
  for (int kt=0; kt<ntiles; ++kt){
    if (kt+1 < ntiles) stageKV(kt+1, cur^1);
    const char* Kc = (const char*)Ks[cur];
    const char* Vc = (const char*)Vs[cur];

    // S = Q K^T  (2 q-subtiles x 4 key-subtiles)
    f32x4 sc[2][4] = {};
    #pragma unroll
    for (int kb=0;kb<64;kb+=32){
      const int kcol = kb + ((lane>>4)<<3);
      bf16x8 kf[4];
      #pragma unroll
      for (int nt=0;nt<4;++nt) kf[nt] = frag_bf16(Kc, (nt<<4)+l15, kcol);
      bf16x8 aq0 = frag_bf16((const char*)Qs, (wv<<5)+l15, kcol);
      bf16x8 aq1 = frag_bf16((const char*)Qs, (wv<<5)+16+l15, kcol);
      __builtin_amdgcn_s_setprio(1);
      #pragma unroll
      for (int nt=0;nt<4;++nt) sc[0][nt] = MFMA(aq0, kf[nt], sc[0][nt]);
      #pragma unroll
      for (int nt=0;nt<4;++nt) sc[1][nt] = MFMA(aq1, kf[nt], sc[1][nt]);
      __builtin_amdgcn_s_setprio(0);
    }

    // p = exp2(s*C2 + tailbias); slots >= cnt -> exact 0 (pad K/V finite garbage is safe)
    float bv4[4];
    #pragma unroll
    for (int nt=0;nt<4;++nt)
      bv4[nt] = ((kt<<6)+(nt<<4)+l15 < cnt) ? 0.f : -1e30f;
    #pragma unroll
    for (int sub=0;sub<2;++sub)
      #pragma unroll
      for (int nt=0;nt<4;++nt){
        f32x4 s = sc[sub][nt];
        #pragma unroll
        for (int j=0;j<4;++j){
          const float p = __builtin_amdgcn_exp2f(fmaf(s[j], C2, bv4[nt]));
          lr[sub][j] += p;
          *(u16*)((char*)Pw + swz((sub<<4)+((lane>>4)<<2)+j, (nt<<4)+l15)) = f2bf(p);
        }
      }
    asm volatile("s_waitcnt lgkmcnt(0)" ::: "memory");
    __builtin_amdgcn_sched_barrier(0);

    // O += P V
    #pragma unroll
    for (int kb=0;kb<64;kb+=32){
      const int kcol = kb + ((lane>>4)<<3);
      bf16x8 vf[4];
      #pragma unroll
      for (int nt=0;nt<4;++nt) vf[nt] = frag_bf16(Vc, (nt<<4)+l15, kcol);
      bf16x8 pa0 = frag_bf16((const char*)Pw, l15, kcol);
      bf16x8 pa1 = frag_bf16((const char*)Pw, 16+l15, kcol);
      __builtin_amdgcn_s_setprio(1);
      #pragma unroll
      for (int nt=0;nt<4;++nt) o[0][nt] = MFMA(pa0, vf[nt], o[0][nt]);
      #pragma unroll
      for (int nt=0;nt<4;++nt) o[1][nt] = MFMA(pa1, vf[nt], o[1][nt]);
      __builtin_amdgcn_s_setprio(0);
    }
    __syncthreads();
    cur ^= 1;
  }

  // epilogue: deferred row-sum reduce, normalize, write
  #pragma unroll
  for (int sub=0;sub<2;++sub)
    #pragma unroll
    for (int j=0;j<4;++j){
      float s = lr[sub][j];
      s += __shfl_xor(s,1); s += __shfl_xor(s,2);
      s += __shfl_xor(s,4); s += __shfl_xor(s,8);
      const float inv = 1.f / fmaxf(s, 1e-30f);
      const int row = (qt<<7) + (wv<<5) + (sub<<4) + ((lane>>4)<<2) + j;
      u16* crow = ctx + ((size_t)((b<<10)+row))*1024 + hc;
      #pragma unroll
      for (int nt=0;nt<4;++nt)
        crow[(nt<<4)+l15] = f2bf(o[sub][nt][j]*inv);
    }
}

extern "C" void kernel_launch(void* const* d_in, const int* in_sizes, int n_in,
                              void* d_out, int out_size, void* d_ws, size_t ws_size,
                              hipStream_t stream) {
  const float* q    = (const float*)d_in[0];
  const float* k    = (const float*)d_in[1];
  const float* v    = (const float*)d_in[2];
  const int*   mask = (const int*)  d_in[3];
  const float* Wq   = (const float*)d_in[4];
  const float* bq   = (const float*)d_in[5];
  const float* Wk   = (const float*)d_in[6];
  const float* bk   = (const float*)d_in[7];
  const float* Wo   = (const float*)d_in[8];
  const float* bo   = (const float*)d_in[9];
  float* out = (float*)d_out;

  // ws: wqb 2M | wkb 2M | wob 2M | qp 8M | kp 8M | vt 8M | ctx 8M | scat 16K | cnts
  char* ws = (char*)d_ws;
  u16* wqb  = (u16*)(ws);
  u16* wkb  = (u16*)(ws +  2097152);
  u16* wob  = (u16*)(ws +  4194304);
  u16* qp   = (u16*)(ws +  6291456);
  u16* kp   = (u16*)(ws + 14680064);
  u16* vtb  = (u16*)(ws + 23068672);
  u16* ctxb = (u16*)(ws + 31457280);
  int* scat = (int*)(ws + 39845888);
  int* cnts = (int*)(ws + 39862272);

  dim3 blk(256);
  mkidx_k<<<4, blk, 0, stream>>>(mask, scat, cnts);
  cvtw_k<<<1536, blk, 0, stream>>>(Wq, Wk, Wo, wqb);
  // q,k projections -> bf16 row-major (k rows compacted via scat)
  gemm_k<0><<<dim3(32,8,2), blk, 0, stream>>>(q, k, wqb, wkb, bq, bk, qp, kp, nullptr, scat);
  // v projection transposed: vt = Wk @ v^T + bk, cols compacted
  gemm_k<1><<<dim3(8,64), blk, 0, stream>>>(v, nullptr, wkb, nullptr, bk, nullptr,
                                            vtb, nullptr, nullptr, scat);
  attn_k<<<512, blk, 0, stream>>>(qp, kp, vtb, cnts, ctxb);
  gemm_k<2><<<dim3(32,16), blk, 0, stream>>>(nullptr, nullptr, ctxb, wob, bo, nullptr,
                                             nullptr, nullptr, out, nullptr);
}

// Round 11
// 107.529 us; speedup vs baseline: 1.0167x; 1.0167x over previous
//
#include <hip/hip_runtime.h>

typedef unsigned short u16;
typedef unsigned int   u32;
typedef __attribute__((ext_vector_type(8))) short bf16x8;
typedef __attribute__((ext_vector_type(4))) float f32x4;
typedef __attribute__((ext_vector_type(4))) u32   u32x4;

#define MFMA(a,b,c) __builtin_amdgcn_mfma_f32_16x16x32_bf16(a,b,c,0,0,0)

// B=4, S=1024, E=1024, H=16, D=64; M = B*S = 4096.

__device__ __forceinline__ u32 cvtpk(float lo, float hi){
  u32 r; asm("v_cvt_pk_bf16_f32 %0, %1, %2" : "=v"(r) : "v"(lo), "v"(hi)); return r;
}
__device__ __forceinline__ u16 f2bf(float f){ return (u16)cvtpk(f,f); }
__device__ __forceinline__ bf16x8 cvt8(f32x4 lo, f32x4 hi){
  u32x4 u;
  u.x = cvtpk(lo[0],lo[1]); u.y = cvtpk(lo[2],lo[3]);
  u.z = cvtpk(hi[0],hi[1]); u.w = cvtpk(hi[2],hi[3]);
  return *(bf16x8*)&u;
}

// XOR swizzle for [row][64 bf16] LDS tiles (128B rows). BYTE offset.
__device__ __forceinline__ int swz(int row, int col){
  return (((row<<6) + col)<<1) ^ ((row&7)<<4);
}

// async global->LDS, 16B/lane; LDS dest wave-uniform (HW adds lane*16)
__device__ __forceinline__ void gl16(const void* g, void* l){
  __builtin_amdgcn_global_load_lds(
      (const __attribute__((address_space(1))) u32*)g,
      (__attribute__((address_space(3))) u32*)l, 16, 0, 0);
}

// stage ROWSx64 bf16 tile via global_load_lds; source-side swizzle ^(row&7).
template<int ROWS>
__device__ __forceinline__ void stage_bf16(const u16* g, size_t ldg, char* lds, int wv, int lane){
  #pragma unroll
  for (int i=0;i<ROWS/32;++i){
    const int r0 = wv*(ROWS/4) + (i<<3);
    const int row = r0 + (lane>>3);
    const int c = ((lane&7) ^ (row&7)) << 3;
    gl16(g + (size_t)row*ldg + c, lds + (r0<<7));
  }
}

__device__ __forceinline__ bf16x8 frag_bf16(const char* lds, int row, int kcol){
  return *(const bf16x8*)(lds + swz(row,kcol));
}

// ---------------- mask compaction: scat[b][s] = compact slot or -1; cnts[b] ----------------
__global__ __launch_bounds__(256) void mkidx_k(const int* __restrict__ mask,
    int* __restrict__ scat, int* __restrict__ cnts)
{
  const int b = blockIdx.x, tid = threadIdx.x, lane = tid&63, wv = tid>>6;
  __shared__ int wsum[4];
  const int4 m = *(const int4*)(mask + (b<<10) + (tid<<2));
  const int c0 = (m.x!=0)+(m.y!=0)+(m.z!=0)+(m.w!=0);
  int pre = c0;
  #pragma unroll
  for (int i=1;i<64;i<<=1){
    int t = __shfl_up(pre, i);
    if (lane >= i) pre += t;
  }
  if (lane==63) wsum[wv] = pre;
  __syncthreads();
  int base = pre - c0;
  #pragma unroll
  for (int w=0;w<4;++w) if (w<wv) base += wsum[w];
  int p = base;
  int* sb = scat + (b<<10) + (tid<<2);
  sb[0] = m.x ? p++ : -1;
  sb[1] = m.y ? p++ : -1;
  sb[2] = m.z ? p++ : -1;
  sb[3] = m.w ? p++ : -1;
  if (tid==255) cnts[b] = p;
}

// ---------------- fp32 -> bf16 convert: Wq|Wk|Wo|q|k|v -> one contiguous bf16 region ----
// 15M elems total: weights 3x1M, inputs 3x4M. out layout = wqb|wkb|wob|qb|kb|vb.
__global__ __launch_bounds__(256) void cvtx_k(
    const float* __restrict__ wq, const float* __restrict__ wk, const float* __restrict__ wo,
    const float* __restrict__ q,  const float* __restrict__ k,  const float* __restrict__ v,
    u16* __restrict__ out)
{
  const size_t i8 = (((size_t)blockIdx.x<<8) + threadIdx.x) << 3;
  const float* src;
  if      (i8 <  1048576u) src = wq + i8;
  else if (i8 <  2097152u) src = wk + (i8 - 1048576u);
  else if (i8 <  3145728u) src = wo + (i8 - 2097152u);
  else if (i8 <  7340032u) src = q  + (i8 - 3145728u);
  else if (i8 < 11534336u) src = k  + (i8 - 7340032u);
  else                     src = v  + (i8 - 11534336u);
  f32x4 lo = *(const f32x4*)src, hi = *(const f32x4*)(src+4);
  *(bf16x8*)(out + i8) = cvt8(lo, hi);
}

// ---------------- GEMM (m97 form): C = A @ B^T (+bias), single-buffer, all-bf16 ----------
// V=0: z=0: A=qb B=wqb out=qp (no scat); z=1: A=kb B=wkb out=kp (row-scat). BN=128.
// V=1: A=wkb, B=vb, bias[m]=bk, out=vt [1024,4096], col-scat. BN=64.
// V=2: A=ctx, B=wob, out f32 [4096,1024]. BN=64.
template<int V>
__global__ __launch_bounds__(256,4) void gemm_k(
    const u16* __restrict__ A0, const u16* __restrict__ A1,
    const u16* __restrict__ W0, const u16* __restrict__ W1,
    const float* __restrict__ b0, const float* __restrict__ b1,
    u16* __restrict__ o0, u16* __restrict__ o1, float* __restrict__ of,
    const int* __restrict__ scat)
{
  constexpr int BN = (V==0)?128:64;
  constexpr int NT = BN/32;            // n-frags per wave
  __shared__ __align__(16) char As[16384];     // 128x64 bf16
  __shared__ __align__(16) char Bs[BN*128];    // BNx64 bf16

  const u16* Aa; const u16* Bb;
  const float* bias; u16* outb=nullptr;
  const int* sc=nullptr;
  if (V==0){
    const int z = blockIdx.z;
    Aa = z?A1:A0; Bb = z?W1:W0; bias = z?b1:b0; outb = z?o1:o0;
    sc = z ? scat : nullptr;
  } else if (V==1){ Aa = W0; Bb = A0; bias = b0; outb = o0; sc = scat; }
  else            { Aa = A0; Bb = W0; bias = b0; }

  const int m0 = blockIdx.x<<7, n0 = blockIdx.y*BN;
  const int tid = threadIdx.x, lane = tid&63, wv = tid>>6;
  const int wm = wv>>1, wn = wv&1, l15 = lane&15, g4 = lane>>4;

  f32x4 acc[4][NT] = {};

  #pragma unroll 1
  for (int kt=0; kt<1024; kt+=64){
    __syncthreads();
    stage_bf16<128>(Aa + (size_t)m0*1024 + kt, 1024, As, wv, lane);
    stage_bf16<BN> (Bb + (size_t)n0*1024 + kt, 1024, Bs, wv, lane);
    __syncthreads();   // drains vmcnt for gl16s

    #pragma unroll
    for (int kb=0;kb<64;kb+=32){
      const int kcol = kb + (g4<<3);
      bf16x8 af[4], bf_[NT];
      #pragma unroll
      for (int t=0;t<4;++t)
        af[t] = frag_bf16(As, (wm<<6) + (t<<4) + l15, kcol);
      #pragma unroll
      for (int t=0;t<NT;++t)
        bf_[t] = frag_bf16(Bs, wn*(BN>>1) + (t<<4) + l15, kcol);
      #pragma unroll
      for (int mt=0;mt<4;++mt)
        #pragma unroll
        for (int nt=0;nt<NT;++nt)
          acc[mt][nt] = MFMA(af[mt], bf_[nt], acc[mt][nt]);
    }
  }

  // epilogue
  f32x4 bmv[4];
  if (V==1){
    #pragma unroll
    for (int mt=0;mt<4;++mt)
      bmv[mt] = *(const f32x4*)(b0 + m0 + (wm<<6) + (mt<<4) + (g4<<2));
  }
  int drow[4][4];     // V0 z=1: scattered dest rows (-1 = drop)
  if (V==0){
    #pragma unroll
    for (int mt=0;mt<4;++mt)
      #pragma unroll
      for (int j=0;j<4;++j){
        const int m = m0 + (wm<<6) + (mt<<4) + (g4<<2) + j;
        int d = m;
        if (sc){ const int c = sc[m]; d = (c<0) ? -1 : ((m & ~1023) | c); }
        drow[mt][j] = d;
      }
  }
  int dcol[NT];       // V1: scattered dest cols (-1 = drop)
  if (V==1){
    #pragma unroll
    for (int nt=0;nt<NT;++nt){
      const int col = n0 + wn*(BN>>1) + (nt<<4) + l15;
      const int c = sc[col];
      dcol[nt] = (c<0) ? -1 : ((col & ~1023) | c);
    }
  }

  #pragma unroll
  for (int nt=0;nt<NT;++nt){
    const int col = n0 + wn*(BN>>1) + (nt<<4) + l15;
    const float bvn = (V==1) ? 0.f : bias[col];
    #pragma unroll
    for (int mt=0;mt<4;++mt){
      const int mb = m0 + (wm<<6) + (mt<<4) + (g4<<2);
      f32x4 a = acc[mt][nt];
      #pragma unroll
      for (int j=0;j<4;++j){
        const float val = a[j] + ((V==1) ? bmv[mt][j] : bvn);
        if (V==2)      of[(size_t)(mb+j)*1024 + col] = val;
        else if (V==1){ if (dcol[nt]>=0) outb[(size_t)(mb+j)*4096 + dcol[nt]] = f2bf(val); }
        else           { if (drow[mt][j]>=0) outb[(size_t)drow[mt][j]*1024 + col] = f2bf(val); }
      }
    }
  }
}

// ---------------- flash attention over COMPACTED keys ----------------
// qp bf16 [B*S,E]; kp bf16 [B*S,E] compact rows; vt bf16 [E,B*S] compact cols.
// cnts[b] = live keys. Tail slots -> -1e30 bias (exp2 -> exact 0).
__global__ __launch_bounds__(256) void attn_k(
    const u16* __restrict__ qp, const u16* __restrict__ kp, const u16* __restrict__ vt,
    const int* __restrict__ cnts, u16* __restrict__ ctx)
{
  const int bid = blockIdx.x;
  const int wg  = (bid&7)*64 + (bid>>3);     // XCD-chunked (512 = 8*64, bijective)
  const int qt = wg&7, h = (wg>>3)&15, b = wg>>7;

  __shared__ __align__(16) u16 Qs[128*64];    // 16KB
  __shared__ __align__(16) u16 Ks[2][64*64];  // 16KB
  __shared__ __align__(16) u16 Vs[2][64*64];  // 16KB (rows=d, cols=key)
  __shared__ __align__(16) u16 Ps[4*32*64];   // 16KB per-wave P

  const int tid = threadIdx.x, lane = tid&63, wv = tid>>6;
  const int hc = h<<6, l15 = lane&15;
  const float C2 = 0.18033688011112042f;      // 0.125 * log2(e)

  const int cnt = cnts[b];
  const int ntiles = (cnt + 63) >> 6;

  { // stage Q (128 x 64)
    const u16* Qg = qp + ((size_t)((b<<10) + (qt<<7)))*1024 + hc;
    #pragma unroll
    for (int i=0;i<4;++i){
      const int r0 = (wv<<5) + (i<<3);
      const int row = r0 + (lane>>3);
      const int c = ((lane&7) ^ (row&7)) << 3;
      gl16(Qg + (size_t)row*1024 + c, (char*)Qs + (r0<<7));
    }
  }

  const u16* Kg = kp + ((size_t)(b<<10))*1024 + hc;
  const u16* Vg = vt + ((size_t)hc)*4096 + (b<<10);

  auto stageKV = [&](int kt2, int bi){
    #pragma unroll
    for (int i=0;i<2;++i){
      const int r0 = (wv<<4) + (i<<3);
      const int row = r0 + (lane>>3);
      const int c = ((lane&7) ^ (row&7)) << 3;
      gl16(Kg + (size_t)((kt2<<6) + row)*1024 + c, (char*)Ks[bi] + (r0<<7));
      gl16(Vg + (size_t)row*4096 + (kt2<<6) + c,  (char*)Vs[bi] + (r0<<7));
    }
  };
  stageKV(0, 0);
  __syncthreads();

  f32x4 o[2][4] = {};
  float lr[2][4] = {};
  u16* Pw = Ps + (wv<<11);
  int cur = 0;

  #pragma unroll 1
  for (int kt=0; kt<ntiles; ++kt){
    if (kt+1 < ntiles) stageKV(kt+1, cur^1);
    const char* Kc = (const char*)Ks[cur];
    const char* Vc = (const char*)Vs[cur];

    // S = Q K^T  (2 q-subtiles x 4 key-subtiles)
    f32x4 sc[2][4] = {};
    #pragma unroll
    for (int kb=0;kb<64;kb+=32){
      const int kcol = kb + ((lane>>4)<<3);
      bf16x8 kf[4];
      #pragma unroll
      for (int nt=0;nt<4;++nt) kf[nt] = frag_bf16(Kc, (nt<<4)+l15, kcol);
      bf16x8 aq0 = frag_bf16((const char*)Qs, (wv<<5)+l15, kcol);
      bf16x8 aq1 = frag_bf16((const char*)Qs, (wv<<5)+16+l15, kcol);
      __builtin_amdgcn_s_setprio(1);
      #pragma unroll
      for (int nt=0;nt<4;++nt) sc[0][nt] = MFMA(aq0, kf[nt], sc[0][nt]);
      #pragma unroll
      for (int nt=0;nt<4;++nt) sc[1][nt] = MFMA(aq1, kf[nt], sc[1][nt]);
      __builtin_amdgcn_s_setprio(0);
    }

    // p = exp2(s*C2 + tailbias); slots >= cnt -> exact 0
    float bv4[4];
    #pragma unroll
    for (int nt=0;nt<4;++nt)
      bv4[nt] = ((kt<<6)+(nt<<4)+l15 < cnt) ? 0.f : -1e30f;
    #pragma unroll
    for (int sub=0;sub<2;++sub)
      #pragma unroll
      for (int nt=0;nt<4;++nt){
        f32x4 s = sc[sub][nt];
        #pragma unroll
        for (int j=0;j<4;++j){
          const float p = __builtin_amdgcn_exp2f(fmaf(s[j], C2, bv4[nt]));
          lr[sub][j] += p;
          *(u16*)((char*)Pw + swz((sub<<4)+((lane>>4)<<2)+j, (nt<<4)+l15)) = f2bf(p);
        }
      }
    asm volatile("s_waitcnt lgkmcnt(0)" ::: "memory");
    __builtin_amdgcn_sched_barrier(0);

    // O += P V
    #pragma unroll
    for (int kb=0;kb<64;kb+=32){
      const int kcol = kb + ((lane>>4)<<3);
      bf16x8 vf[4];
      #pragma unroll
      for (int nt=0;nt<4;++nt) vf[nt] = frag_bf16(Vc, (nt<<4)+l15, kcol);
      bf16x8 pa0 = frag_bf16((const char*)Pw, l15, kcol);
      bf16x8 pa1 = frag_bf16((const char*)Pw, 16+l15, kcol);
      __builtin_amdgcn_s_setprio(1);
      #pragma unroll
      for (int nt=0;nt<4;++nt) o[0][nt] = MFMA(pa0, vf[nt], o[0][nt]);
      #pragma unroll
      for (int nt=0;nt<4;++nt) o[1][nt] = MFMA(pa1, vf[nt], o[1][nt]);
      __builtin_amdgcn_s_setprio(0);
    }
    __syncthreads();
    cur ^= 1;
  }

  // epilogue: deferred row-sum reduce, normalize, write
  #pragma unroll
  for (int sub=0;sub<2;++sub)
    #pragma unroll
    for (int j=0;j<4;++j){
      float s = lr[sub][j];
      s += __shfl_xor(s,1); s += __shfl_xor(s,2);
      s += __shfl_xor(s,4); s += __shfl_xor(s,8);
      const float inv = 1.f / fmaxf(s, 1e-30f);
      const int row = (qt<<7) + (wv<<5) + (sub<<4) + ((lane>>4)<<2) + j;
      u16* crow = ctx + ((size_t)((b<<10)+row))*1024 + hc;
      #pragma unroll
      for (int nt=0;nt<4;++nt)
        crow[(nt<<4)+l15] = f2bf(o[sub][nt][j]*inv);
    }
}

extern "C" void kernel_launch(void* const* d_in, const int* in_sizes, int n_in,
                              void* d_out, int out_size, void* d_ws, size_t ws_size,
                              hipStream_t stream) {
  const float* q    = (const float*)d_in[0];
  const float* k    = (const float*)d_in[1];
  const float* v    = (const float*)d_in[2];
  const int*   mask = (const int*)  d_in[3];
  const float* Wq   = (const float*)d_in[4];
  const float* bq   = (const float*)d_in[5];
  const float* Wk   = (const float*)d_in[6];
  const float* bk   = (const float*)d_in[7];
  const float* Wo   = (const float*)d_in[8];
  const float* bo   = (const float*)d_in[9];
  float* out = (float*)d_out;

  // ws (ws_size = 256MB per the observed poison fill):
  // bf16 region: wqb 2M | wkb 2M | wob 2M | qb 8M | kb 8M | vb 8M   (cvtx output, 30M)
  // then: qp 8M | kp 8M | vt 8M | ctx 8M | scat 16K | cnts
  char* ws = (char*)d_ws;
  u16* wqb  = (u16*)(ws);
  u16* wkb  = (u16*)(ws +  2097152);
  u16* wob  = (u16*)(ws +  4194304);
  u16* qb   = (u16*)(ws +  6291456);
  u16* kb   = (u16*)(ws + 14680064);
  u16* vb   = (u16*)(ws + 23068672);
  u16* qp   = (u16*)(ws + 31457280);
  u16* kp   = (u16*)(ws + 39845888);
  u16* vtb  = (u16*)(ws + 48234496);
  u16* ctxb = (u16*)(ws + 56623104);
  int* scat = (int*)(ws + 65011712);
  int* cnts = (int*)(ws + 65028096);

  dim3 blk(256);
  mkidx_k<<<4, blk, 0, stream>>>(mask, scat, cnts);
  cvtx_k<<<7680, blk, 0, stream>>>(Wq, Wk, Wo, q, k, v, wqb);
  // q,k projections (k rows compacted via scat)
  gemm_k<0><<<dim3(32,8,2), blk, 0, stream>>>(qb, kb, wqb, wkb, bq, bk, qp, kp, nullptr, scat);
  // v projection transposed: vt = Wk @ v^T + bk, cols compacted
  gemm_k<1><<<dim3(8,64), blk, 0, stream>>>(vb, nullptr, wkb, nullptr, bk, nullptr,
                                            vtb, nullptr, nullptr, scat);
  attn_k<<<512, blk, 0, stream>>>(qp, kp, vtb, cnts, ctxb);
  gemm_k<2><<<dim3(32,16), blk, 0, stream>>>(ctxb, nullptr, wob, nullptr, bo, nullptr,
                                             nullptr, nullptr, out, nullptr);
}

// Round 13
// 91.175 us; speedup vs baseline: 1.1990x; 1.1794x over previous
//
#include <hip/hip_runtime.h>

typedef unsigned short u16;
typedef unsigned int   u32;
typedef __attribute__((ext_vector_type(8))) short bf16x8;
typedef __attribute__((ext_vector_type(4))) float f32x4;
typedef __attribute__((ext_vector_type(4))) u32   u32x4;

#define MFMA(a,b,c) __builtin_amdgcn_mfma_f32_16x16x32_bf16(a,b,c,0,0,0)

// B=4, S=1024, E=1024, H=16, D=64; M = B*S = 4096.

__device__ __forceinline__ u32 cvtpk(float lo, float hi){
  u32 r; asm("v_cvt_pk_bf16_f32 %0, %1, %2" : "=v"(r) : "v"(lo), "v"(hi)); return r;
}
__device__ __forceinline__ u16 f2bf(float f){ return (u16)cvtpk(f,f); }
__device__ __forceinline__ bf16x8 cvt8(f32x4 lo, f32x4 hi){
  u32x4 u;
  u.x = cvtpk(lo[0],lo[1]); u.y = cvtpk(lo[2],lo[3]);
  u.z = cvtpk(hi[0],hi[1]); u.w = cvtpk(hi[2],hi[3]);
  return *(bf16x8*)&u;
}

// XOR swizzle for [row][64 bf16] LDS tiles (128B rows). BYTE offset.
__device__ __forceinline__ int swz(int row, int col){
  return (((row<<6) + col)<<1) ^ ((row&7)<<4);
}

// async global->LDS, 16B/lane; LDS dest wave-uniform (HW adds lane*16)
__device__ __forceinline__ void gl16(const void* g, void* l){
  __builtin_amdgcn_global_load_lds(
      (const __attribute__((address_space(1))) u32*)g,
      (__attribute__((address_space(3))) u32*)l, 16, 0, 0);
}

// stage ROWSx64 bf16 tile via global_load_lds; source-side swizzle ^(row&7).
template<int ROWS>
__device__ __forceinline__ void stage_bf16(const u16* g, size_t ldg, char* lds, int wv, int lane){
  #pragma unroll
  for (int i=0;i<ROWS/32;++i){
    const int r0 = wv*(ROWS/4) + (i<<3);
    const int row = r0 + (lane>>3);
    const int c = ((lane&7) ^ (row&7)) << 3;
    gl16(g + (size_t)row*ldg + c, lds + (r0<<7));
  }
}

__device__ __forceinline__ bf16x8 frag_bf16(const char* lds, int row, int kcol){
  return *(const bf16x8*)(lds + swz(row,kcol));
}

// ---------------- cvtx + mkidx fused ----------------
// blocks 0..7679: fp32->bf16 convert Wq|Wk|Wo|q|k|v -> contiguous bf16 region.
// blocks 7680..7683: per-batch mask prefix-sum -> scat (compact slot or -1), cnts.
__global__ __launch_bounds__(256) void prep_k(
    const float* __restrict__ wq, const float* __restrict__ wk, const float* __restrict__ wo,
    const float* __restrict__ q,  const float* __restrict__ k,  const float* __restrict__ v,
    u16* __restrict__ out,
    const int* __restrict__ mask, int* __restrict__ scat, int* __restrict__ cnts)
{
  const int tid = threadIdx.x;
  if (blockIdx.x < 7680){
    const size_t i8 = (((size_t)blockIdx.x<<8) + tid) << 3;
    const float* src;
    if      (i8 <  1048576u) src = wq + i8;
    else if (i8 <  2097152u) src = wk + (i8 - 1048576u);
    else if (i8 <  3145728u) src = wo + (i8 - 2097152u);
    else if (i8 <  7340032u) src = q  + (i8 - 3145728u);
    else if (i8 < 11534336u) src = k  + (i8 - 7340032u);
    else                     src = v  + (i8 - 11534336u);
    f32x4 lo = *(const f32x4*)src, hi = *(const f32x4*)(src+4);
    *(bf16x8*)(out + i8) = cvt8(lo, hi);
  } else {
    const int b = blockIdx.x - 7680, lane = tid&63, wv = tid>>6;
    __shared__ int wsum[4];
    const int4 m = *(const int4*)(mask + (b<<10) + (tid<<2));
    const int c0 = (m.x!=0)+(m.y!=0)+(m.z!=0)+(m.w!=0);
    int pre = c0;
    #pragma unroll
    for (int i=1;i<64;i<<=1){
      int t = __shfl_up(pre, i);
      if (lane >= i) pre += t;
    }
    if (lane==63) wsum[wv] = pre;
    __syncthreads();
    int base = pre - c0;
    #pragma unroll
    for (int w=0;w<4;++w) if (w<wv) base += wsum[w];
    int p = base;
    int* sb = scat + (b<<10) + (tid<<2);
    sb[0] = m.x ? p++ : -1;
    sb[1] = m.y ? p++ : -1;
    sb[2] = m.z ? p++ : -1;
    sb[3] = m.w ? p++ : -1;
    if (tid==255) cnts[b] = p;
  }
}

// ---------------- projection GEMM body (m97 form, all-bf16, single-buffer) ----------------
// V=0: BN=128, C=A@B^T+bias[n], out bf16 rows (scattered if sc). A:[.,1024] B:[1024,1024]
// V=1: BN=64,  C=A@B^T+bias[m], out bf16 vt[1024,4096], cols scattered via sc.
template<int V>
__device__ __forceinline__ void proj_body(
    int m0, int n0, const u16* __restrict__ Aa, const u16* __restrict__ Bb,
    const float* __restrict__ bias, u16* __restrict__ outb, const int* __restrict__ sc,
    char* As, char* Bs)
{
  constexpr int BN = (V==0)?128:64;
  constexpr int NT = BN/32;
  const int tid = threadIdx.x, lane = tid&63, wv = tid>>6;
  const int wm = wv>>1, wn = wv&1, l15 = lane&15, g4 = lane>>4;

  f32x4 acc[4][NT] = {};

  #pragma unroll 1
  for (int kt=0; kt<1024; kt+=64){
    __syncthreads();
    stage_bf16<128>(Aa + (size_t)m0*1024 + kt, 1024, As, wv, lane);
    stage_bf16<BN> (Bb + (size_t)n0*1024 + kt, 1024, Bs, wv, lane);
    __syncthreads();

    #pragma unroll
    for (int kb=0;kb<64;kb+=32){
      const int kcol = kb + (g4<<3);
      bf16x8 af[4], bf_[NT];
      #pragma unroll
      for (int t=0;t<4;++t)
        af[t] = frag_bf16(As, (wm<<6) + (t<<4) + l15, kcol);
      #pragma unroll
      for (int t=0;t<NT;++t)
        bf_[t] = frag_bf16(Bs, wn*(BN>>1) + (t<<4) + l15, kcol);
      #pragma unroll
      for (int mt=0;mt<4;++mt)
        #pragma unroll
        for (int nt=0;nt<NT;++nt)
          acc[mt][nt] = MFMA(af[mt], bf_[nt], acc[mt][nt]);
    }
  }

  // epilogue
  f32x4 bmv[4];
  if (V==1){
    #pragma unroll
    for (int mt=0;mt<4;++mt)
      bmv[mt] = *(const f32x4*)(bias + m0 + (wm<<6) + (mt<<4) + (g4<<2));
  }
  int drow[4][4];
  if (V==0){
    #pragma unroll
    for (int mt=0;mt<4;++mt)
      #pragma unroll
      for (int j=0;j<4;++j){
        const int m = m0 + (wm<<6) + (mt<<4) + (g4<<2) + j;
        int d = m;
        if (sc){ const int c = sc[m]; d = (c<0) ? -1 : ((m & ~1023) | c); }
        drow[mt][j] = d;
      }
  }
  int dcol[NT];
  if (V==1){
    #pragma unroll
    for (int nt=0;nt<NT;++nt){
      const int col = n0 + wn*(BN>>1) + (nt<<4) + l15;
      const int c = sc[col];
      dcol[nt] = (c<0) ? -1 : ((col & ~1023) | c);
    }
  }

  #pragma unroll
  for (int nt=0;nt<NT;++nt){
    const int col = n0 + wn*(BN>>1) + (nt<<4) + l15;
    const float bvn = (V==1) ? 0.f : bias[col];
    #pragma unroll
    for (int mt=0;mt<4;++mt){
      const int mb = m0 + (wm<<6) + (mt<<4) + (g4<<2);
      f32x4 a = acc[mt][nt];
      #pragma unroll
      for (int j=0;j<4;++j){
        const float val = a[j] + ((V==1) ? bmv[mt][j] : bvn);
        if (V==1){ if (dcol[nt]>=0)     outb[(size_t)(mb+j)*4096 + dcol[nt]] = f2bf(val); }
        else      { if (drow[mt][j]>=0) outb[(size_t)drow[mt][j]*1024 + col] = f2bf(val); }
      }
    }
  }
}

// ---------------- all three projections in ONE launch (1024 blocks) ----------------
// bid 0..255:   q-proj, 32x8 tiles of 128x128 (no scat)
// bid 256..511: k-proj, 32x8 tiles (row-scat)
// bid 512..1023: v^T-proj, 8x64 tiles of 128x64 (col-scat)
__global__ __launch_bounds__(256,4) void proj_k(
    const u16* __restrict__ qb, const u16* __restrict__ kb, const u16* __restrict__ vb,
    const u16* __restrict__ wqb, const u16* __restrict__ wkb,
    const float* __restrict__ bq, const float* __restrict__ bk,
    u16* __restrict__ qp, u16* __restrict__ kp, u16* __restrict__ vt,
    const int* __restrict__ scat)
{
  __shared__ __align__(16) char As[16384];
  __shared__ __align__(16) char Bs[16384];
  const int bid = blockIdx.x;
  if (bid < 512){
    const int z = bid>>8, local = bid&255;            // 256 blocks per projection
    proj_body<0>((local&31)<<7, ((local>>5)&7)<<7,
                 z?kb:qb, z?wkb:wqb, z?bk:bq, z?kp:qp, z?scat:nullptr, As, Bs);
  } else {
    const int local = bid-512;                        // 512 blocks: 8 m-tiles x 64 n-tiles
    proj_body<1>((local&7)<<7, (local>>3)<<6, wkb, vb, bk, vt, scat, As, Bs);
  }
}

// ---------------- output projection: out = ctx @ Wo^T + bo (f32 out) ----------------
__global__ __launch_bounds__(256,4) void oproj_k(
    const u16* __restrict__ ctx, const u16* __restrict__ wob,
    const float* __restrict__ bo, float* __restrict__ of)
{
  constexpr int BN = 64, NT = 2;
  __shared__ __align__(16) char As[16384];
  __shared__ __align__(16) char Bs[BN*128];
  const int m0 = blockIdx.x<<7, n0 = blockIdx.y*BN;
  const int tid = threadIdx.x, lane = tid&63, wv = tid>>6;
  const int wm = wv>>1, wn = wv&1, l15 = lane&15, g4 = lane>>4;

  f32x4 acc[4][NT] = {};

  #pragma unroll 1
  for (int kt=0; kt<1024; kt+=64){
    __syncthreads();
    stage_bf16<128>(ctx + (size_t)m0*1024 + kt, 1024, As, wv, lane);
    stage_bf16<BN> (wob + (size_t)n0*1024 + kt, 1024, Bs, wv, lane);
    __syncthreads();

    #pragma unroll
    for (int kb=0;kb<64;kb+=32){
      const int kcol = kb + (g4<<3);
      bf16x8 af[4], bf_[NT];
      #pragma unroll
      for (int t=0;t<4;++t)
        af[t] = frag_bf16(As, (wm<<6) + (t<<4) + l15, kcol);
      #pragma unroll
      for (int t=0;t<NT;++t)
        bf_[t] = frag_bf16(Bs, wn*(BN>>1) + (t<<4) + l15, kcol);
      #pragma unroll
      for (int mt=0;mt<4;++mt)
        #pragma unroll
        for (int nt=0;nt<NT;++nt)
          acc[mt][nt] = MFMA(af[mt], bf_[nt], acc[mt][nt]);
    }
  }

  #pragma unroll
  for (int nt=0;nt<NT;++nt){
    const int col = n0 + wn*(BN>>1) + (nt<<4) + l15;
    const float bvn = bo[col];
    #pragma unroll
    for (int mt=0;mt<4;++mt){
      const int mb = m0 + (wm<<6) + (mt<<4) + (g4<<2);
      f32x4 a = acc[mt][nt];
      #pragma unroll
      for (int j=0;j<4;++j)
        of[(size_t)(mb+j)*1024 + col] = a[j] + bvn;
    }
  }
}

// ---------------- flash attention over COMPACTED keys ----------------
// qp bf16 [B*S,E]; kp bf16 [B*S,E] compact rows; vt bf16 [E,B*S] compact cols.
// cnts[b] = live keys. Tail slots -> -1e30 bias (exp2 -> exact 0).
__global__ __launch_bounds__(256) void attn_k(
    const u16* __restrict__ qp, const u16* __restrict__ kp, const u16* __restrict__ vt,
    const int* __restrict__ cnts, u16* __restrict__ ctx)
{
  const int bid = blockIdx.x;
  const int wg  = (bid&7)*64 + (bid>>3);     // XCD-chunked (512 = 8*64, bijective)
  const int qt = wg&7, h = (wg>>3)&15, b = wg>>7;

  __shared__ __align__(16) u16 Qs[128*64];    // 16KB
  __shared__ __align__(16) u16 Ks[2][64*64];  // 16KB
  __shared__ __align__(16) u16 Vs[2][64*64];  // 16KB (rows=d, cols=key)
  __shared__ __align__(16) u16 Ps[4*32*64];   // 16KB per-wave P

  const int tid = threadIdx.x, lane = tid&63, wv = tid>>6;
  const int hc = h<<6, l15 = lane&15;
  const float C2 = 0.18033688011112042f;      // 0.125 * log2(e)

  const int cnt = cnts[b];
  const int ntiles = (cnt + 63) >> 6;

  { // stage Q (128 x 64)
    const u16* Qg = qp + ((size_t)((b<<10) + (qt<<7)))*1024 + hc;
    #pragma unroll
    for (int i=0;i<4;++i){
      const int r0 = (wv<<5) + (i<<3);
      const int row = r0 + (lane>>3);
      const int c = ((lane&7) ^ (row&7)) << 3;
      gl16(Qg + (size_t)row*1024 + c, (char*)Qs + (r0<<7));
    }
  }

  const u16* Kg = kp + ((size_t)(b<<10))*1024 + hc;
  const u16* Vg = vt + ((size_t)hc)*4096 + (b<<10);

  auto stageKV = [&](int kt2, int bi){
    #pragma unroll
    for (int i=0;i<2;++i){
      const int r0 = (wv<<4) + (i<<3);
      const int row = r0 + (lane>>3);
      const int c = ((lane&7) ^ (row&7)) << 3;
      gl16(Kg + (size_t)((kt2<<6) + row)*1024 + c, (char*)Ks[bi] + (r0<<7));
      gl16(Vg + (size_t)row*4096 + (kt2<<6) + c,  (char*)Vs[bi] + (r0<<7));
    }
  };
  stageKV(0, 0);
  __syncthreads();

  f32x4 o[2][4] = {};
  float lr[2][4] = {};
  u16* Pw = Ps + (wv<<11);
  int cur = 0;

  #pragma unroll 1
  for (int kt=0; kt<ntiles; ++kt){
    if (kt+1 < ntiles) stageKV(kt+1, cur^1);
    const char* Kc = (const char*)Ks[cur];
    const char* Vc = (const char*)Vs[cur];

    // S = Q K^T  (2 q-subtiles x 4 key-subtiles)
    f32x4 sc[2][4] = {};
    #pragma unroll
    for (int kb=0;kb<64;kb+=32){
      const int kcol = kb + ((lane>>4)<<3);
      bf16x8 kf[4];
      #pragma unroll
      for (int nt=0;nt<4;++nt) kf[nt] = frag_bf16(Kc, (nt<<4)+l15, kcol);
      bf16x8 aq0 = frag_bf16((const char*)Qs, (wv<<5)+l15, kcol);
      bf16x8 aq1 = frag_bf16((const char*)Qs, (wv<<5)+16+l15, kcol);
      __builtin_amdgcn_s_setprio(1);
      #pragma unroll
      for (int nt=0;nt<4;++nt) sc[0][nt] = MFMA(aq0, kf[nt], sc[0][nt]);
      #pragma unroll
      for (int nt=0;nt<4;++nt) sc[1][nt] = MFMA(aq1, kf[nt], sc[1][nt]);
      __builtin_amdgcn_s_setprio(0);
    }

    // p = exp2(s*C2 + tailbias); slots >= cnt -> exact 0
    float bv4[4];
    #pragma unroll
    for (int nt=0;nt<4;++nt)
      bv4[nt] = ((kt<<6)+(nt<<4)+l15 < cnt) ? 0.f : -1e30f;
    #pragma unroll
    for (int sub=0;sub<2;++sub)
      #pragma unroll
      for (int nt=0;nt<4;++nt){
        f32x4 s = sc[sub][nt];
        #pragma unroll
        for (int j=0;j<4;++j){
          const float p = __builtin_amdgcn_exp2f(fmaf(s[j], C2, bv4[nt]));
          lr[sub][j] += p;
          *(u16*)((char*)Pw + swz((sub<<4)+((lane>>4)<<2)+j, (nt<<4)+l15)) = f2bf(p);
        }
      }
    asm volatile("s_waitcnt lgkmcnt(0)" ::: "memory");
    __builtin_amdgcn_sched_barrier(0);

    // O += P V
    #pragma unroll
    for (int kb=0;kb<64;kb+=32){
      const int kcol = kb + ((lane>>4)<<3);
      bf16x8 vf[4];
      #pragma unroll
      for (int nt=0;nt<4;++nt) vf[nt] = frag_bf16(Vc, (nt<<4)+l15, kcol);
      bf16x8 pa0 = frag_bf16((const char*)Pw, l15, kcol);
      bf16x8 pa1 = frag_bf16((const char*)Pw, 16+l15, kcol);
      __builtin_amdgcn_s_setprio(1);
      #pragma unroll
      for (int nt=0;nt<4;++nt) o[0][nt] = MFMA(pa0, vf[nt], o[0][nt]);
      #pragma unroll
      for (int nt=0;nt<4;++nt) o[1][nt] = MFMA(pa1, vf[nt], o[1][nt]);
      __builtin_amdgcn_s_setprio(0);
    }
    __syncthreads();
    cur ^= 1;
  }

  // epilogue: deferred row-sum reduce, normalize, write
  #pragma unroll
  for (int sub=0;sub<2;++sub)
    #pragma unroll
    for (int j=0;j<4;++j){
      float s = lr[sub][j];
      s += __shfl_xor(s,1); s += __shfl_xor(s,2);
      s += __shfl_xor(s,4); s += __shfl_xor(s,8);
      const float inv = 1.f / fmaxf(s, 1e-30f);
      const int row = (qt<<7) + (wv<<5) + (sub<<4) + ((lane>>4)<<2) + j;
      u16* crow = ctx + ((size_t)((b<<10)+row))*1024 + hc;
      #pragma unroll
      for (int nt=0;nt<4;++nt)
        crow[(nt<<4)+l15] = f2bf(o[sub][nt][j]*inv);
    }
}

extern "C" void kernel_launch(void* const* d_in, const int* in_sizes, int n_in,
                              void* d_out, int out_size, void* d_ws, size_t ws_size,
                              hipStream_t stream) {
  const float* q    = (const float*)d_in[0];
  const float* k    = (const float*)d_in[1];
  const float* v    = (const float*)d_in[2];
  const int*   mask = (const int*)  d_in[3];
  const float* Wq   = (const float*)d_in[4];
  const float* bq   = (const float*)d_in[5];
  const float* Wk   = (const float*)d_in[6];
  const float* bk   = (const float*)d_in[7];
  const float* Wo   = (const float*)d_in[8];
  const float* bo   = (const float*)d_in[9];
  float* out = (float*)d_out;

  // ws layout: wqb 2M | wkb 2M | wob 2M | qb 8M | kb 8M | vb 8M | qp 8M | kp 8M
  //            | vt 8M | ctx 8M | scat 16K | cnts
  char* ws = (char*)d_ws;
  u16* wqb  = (u16*)(ws);
  u16* wkb  = (u16*)(ws +  2097152);
  u16* wob  = (u16*)(ws +  4194304);
  u16* qb   = (u16*)(ws +  6291456);
  u16* kb   = (u16*)(ws + 14680064);
  u16* vb   = (u16*)(ws + 23068672);
  u16* qp   = (u16*)(ws + 31457280);
  u16* kp   = (u16*)(ws + 39845888);
  u16* vtb  = (u16*)(ws + 48234496);
  u16* ctxb = (u16*)(ws + 56623104);
  int* scat = (int*)(ws + 65011712);
  int* cnts = (int*)(ws + 65028096);

  dim3 blk(256);
  prep_k<<<7684, blk, 0, stream>>>(Wq, Wk, Wo, q, k, v, wqb, mask, scat, cnts);
  proj_k<<<1024, blk, 0, stream>>>(qb, kb, vb, wqb, wkb, bq, bk, qp, kp, vtb, scat);
  attn_k<<<512, blk, 0, stream>>>(qp, kp, vtb, cnts, ctxb);
  oproj_k<<<dim3(32,16), blk, 0, stream>>>(ctxb, wob, bo, out);
}

// Round 14
// 90.341 us; speedup vs baseline: 1.2101x; 1.0092x over previous
//
#include <hip/hip_runtime.h>

typedef unsigned short u16;
typedef unsigned int   u32;
typedef __attribute__((ext_vector_type(8))) short bf16x8;
typedef __attribute__((ext_vector_type(4))) float f32x4;
typedef __attribute__((ext_vector_type(4))) u32   u32x4;

#define MFMA(a,b,c) __builtin_amdgcn_mfma_f32_16x16x32_bf16(a,b,c,0,0,0)

// B=4, S=1024, E=1024, H=16, D=64; M = B*S = 4096.

__device__ __forceinline__ u32 cvtpk(float lo, float hi){
  u32 r; asm("v_cvt_pk_bf16_f32 %0, %1, %2" : "=v"(r) : "v"(lo), "v"(hi)); return r;
}
__device__ __forceinline__ u16 f2bf(float f){ return (u16)cvtpk(f,f); }
__device__ __forceinline__ bf16x8 cvt8(f32x4 lo, f32x4 hi){
  u32x4 u;
  u.x = cvtpk(lo[0],lo[1]); u.y = cvtpk(lo[2],lo[3]);
  u.z = cvtpk(hi[0],hi[1]); u.w = cvtpk(hi[2],hi[3]);
  return *(bf16x8*)&u;
}

// XOR swizzle for [row][64 bf16] LDS tiles (128B rows). BYTE offset.
__device__ __forceinline__ int swz(int row, int col){
  return (((row<<6) + col)<<1) ^ ((row&7)<<4);
}

// async global->LDS, 16B/lane; LDS dest wave-uniform (HW adds lane*16)
__device__ __forceinline__ void gl16(const void* g, void* l){
  __builtin_amdgcn_global_load_lds(
      (const __attribute__((address_space(1))) u32*)g,
      (__attribute__((address_space(3))) u32*)l, 16, 0, 0);
}

// stage ROWSx64 bf16 tile via global_load_lds; source-side swizzle ^(row&7).
template<int ROWS>
__device__ __forceinline__ void stage_bf16(const u16* g, size_t ldg, char* lds, int wv, int lane){
  #pragma unroll
  for (int i=0;i<ROWS/32;++i){
    const int r0 = wv*(ROWS/4) + (i<<3);
    const int row = r0 + (lane>>3);
    const int c = ((lane&7) ^ (row&7)) << 3;
    gl16(g + (size_t)row*ldg + c, lds + (r0<<7));
  }
}

__device__ __forceinline__ bf16x8 frag_bf16(const char* lds, int row, int kcol){
  return *(const bf16x8*)(lds + swz(row,kcol));
}

// ---------------- cvtx + mkidx fused ----------------
// blocks 0..7679: fp32->bf16 convert Wq|Wk|Wo|q|k|v -> contiguous bf16 region.
// blocks 7680..7683: per-batch mask prefix-sum -> scat (compact slot or -1), cnts.
__global__ __launch_bounds__(256) void prep_k(
    const float* __restrict__ wq, const float* __restrict__ wk, const float* __restrict__ wo,
    const float* __restrict__ q,  const float* __restrict__ k,  const float* __restrict__ v,
    u16* __restrict__ out,
    const int* __restrict__ mask, int* __restrict__ scat, int* __restrict__ cnts)
{
  const int tid = threadIdx.x;
  if (blockIdx.x < 7680){
    const size_t i8 = (((size_t)blockIdx.x<<8) + tid) << 3;
    const float* src;
    if      (i8 <  1048576u) src = wq + i8;
    else if (i8 <  2097152u) src = wk + (i8 - 1048576u);
    else if (i8 <  3145728u) src = wo + (i8 - 2097152u);
    else if (i8 <  7340032u) src = q  + (i8 - 3145728u);
    else if (i8 < 11534336u) src = k  + (i8 - 7340032u);
    else                     src = v  + (i8 - 11534336u);
    f32x4 lo = *(const f32x4*)src, hi = *(const f32x4*)(src+4);
    *(bf16x8*)(out + i8) = cvt8(lo, hi);
  } else {
    const int b = blockIdx.x - 7680, lane = tid&63, wv = tid>>6;
    __shared__ int wsum[4];
    const int4 m = *(const int4*)(mask + (b<<10) + (tid<<2));
    const int c0 = (m.x!=0)+(m.y!=0)+(m.z!=0)+(m.w!=0);
    int pre = c0;
    #pragma unroll
    for (int i=1;i<64;i<<=1){
      int t = __shfl_up(pre, i);
      if (lane >= i) pre += t;
    }
    if (lane==63) wsum[wv] = pre;
    __syncthreads();
    int base = pre - c0;
    #pragma unroll
    for (int w=0;w<4;++w) if (w<wv) base += wsum[w];
    int p = base;
    int* sb = scat + (b<<10) + (tid<<2);
    sb[0] = m.x ? p++ : -1;
    sb[1] = m.y ? p++ : -1;
    sb[2] = m.z ? p++ : -1;
    sb[3] = m.w ? p++ : -1;
    if (tid==255) cnts[b] = p;
  }
}

// ---------------- projection GEMM body (m97 form, all-bf16, single-buffer, 128x128) ------
// V=0: C=A@B^T+bias[n], out bf16 rows (scattered if sc).
// V=1: C=A@B^T+bias[m], out bf16 vt[1024,4096], cols scattered via sc.
template<int V>
__device__ __forceinline__ void proj_body(
    int m0, int n0, const u16* __restrict__ Aa, const u16* __restrict__ Bb,
    const float* __restrict__ bias, u16* __restrict__ outb, const int* __restrict__ sc,
    char* As, char* Bs)
{
  constexpr int NT = 4;
  const int tid = threadIdx.x, lane = tid&63, wv = tid>>6;
  const int wm = wv>>1, wn = wv&1, l15 = lane&15, g4 = lane>>4;

  f32x4 acc[4][NT] = {};

  #pragma unroll 1
  for (int kt=0; kt<1024; kt+=64){
    __syncthreads();
    stage_bf16<128>(Aa + (size_t)m0*1024 + kt, 1024, As, wv, lane);
    stage_bf16<128>(Bb + (size_t)n0*1024 + kt, 1024, Bs, wv, lane);
    __syncthreads();

    #pragma unroll
    for (int kb=0;kb<64;kb+=32){
      const int kcol = kb + (g4<<3);
      bf16x8 af[4], bf_[NT];
      #pragma unroll
      for (int t=0;t<4;++t)
        af[t] = frag_bf16(As, (wm<<6) + (t<<4) + l15, kcol);
      #pragma unroll
      for (int t=0;t<NT;++t)
        bf_[t] = frag_bf16(Bs, (wn<<6) + (t<<4) + l15, kcol);
      #pragma unroll
      for (int mt=0;mt<4;++mt)
        #pragma unroll
        for (int nt=0;nt<NT;++nt)
          acc[mt][nt] = MFMA(af[mt], bf_[nt], acc[mt][nt]);
    }
  }

  // epilogue
  f32x4 bmv[4];
  if (V==1){
    #pragma unroll
    for (int mt=0;mt<4;++mt)
      bmv[mt] = *(const f32x4*)(bias + m0 + (wm<<6) + (mt<<4) + (g4<<2));
  }
  int drow[4][4];
  if (V==0){
    #pragma unroll
    for (int mt=0;mt<4;++mt)
      #pragma unroll
      for (int j=0;j<4;++j){
        const int m = m0 + (wm<<6) + (mt<<4) + (g4<<2) + j;
        int d = m;
        if (sc){ const int c = sc[m]; d = (c<0) ? -1 : ((m & ~1023) | c); }
        drow[mt][j] = d;
      }
  }
  int dcol[NT];
  if (V==1){
    #pragma unroll
    for (int nt=0;nt<NT;++nt){
      const int col = n0 + (wn<<6) + (nt<<4) + l15;
      const int c = sc[col];
      dcol[nt] = (c<0) ? -1 : ((col & ~1023) | c);
    }
  }

  #pragma unroll
  for (int nt=0;nt<NT;++nt){
    const int col = n0 + (wn<<6) + (nt<<4) + l15;
    const float bvn = (V==1) ? 0.f : bias[col];
    #pragma unroll
    for (int mt=0;mt<4;++mt){
      const int mb = m0 + (wm<<6) + (mt<<4) + (g4<<2);
      f32x4 a = acc[mt][nt];
      #pragma unroll
      for (int j=0;j<4;++j){
        const float val = a[j] + ((V==1) ? bmv[mt][j] : bvn);
        if (V==1){ if (dcol[nt]>=0)     outb[(size_t)(mb+j)*4096 + dcol[nt]] = f2bf(val); }
        else      { if (drow[mt][j]>=0) outb[(size_t)drow[mt][j]*1024 + col] = f2bf(val); }
      }
    }
  }
}

// ---------------- all three projections in ONE launch (768 blocks, all 128x128) ----------
// bid 0..255:   q-proj, 32x8 tiles (no scat)
// bid 256..511: k-proj, 32x8 tiles (row-scat)
// bid 512..767: v^T-proj, 8x32 tiles (col-scat)
__global__ __launch_bounds__(256,4) void proj_k(
    const u16* __restrict__ qb, const u16* __restrict__ kb, const u16* __restrict__ vb,
    const u16* __restrict__ wqb, const u16* __restrict__ wkb,
    const float* __restrict__ bq, const float* __restrict__ bk,
    u16* __restrict__ qp, u16* __restrict__ kp, u16* __restrict__ vt,
    const int* __restrict__ scat)
{
  __shared__ __align__(16) char As[16384];
  __shared__ __align__(16) char Bs[16384];
  const int bid = blockIdx.x;
  if (bid < 512){
    const int z = bid>>8, local = bid&255;            // 256 blocks per projection
    proj_body<0>((local&31)<<7, ((local>>5)&7)<<7,
                 z?kb:qb, z?wkb:wqb, z?bk:bq, z?kp:qp, z?scat:nullptr, As, Bs);
  } else {
    const int local = bid-512;                        // 256 blocks: 8 m-tiles x 32 n-tiles
    proj_body<1>((local&7)<<7, (local>>3)<<7, wkb, vb, bk, vt, scat, As, Bs);
  }
}

// ---------------- output projection: out = ctx @ Wo^T + bo (f32 out) ----------------
__global__ __launch_bounds__(256,4) void oproj_k(
    const u16* __restrict__ ctx, const u16* __restrict__ wob,
    const float* __restrict__ bo, float* __restrict__ of)
{
  constexpr int BN = 64, NT = 2;
  __shared__ __align__(16) char As[16384];
  __shared__ __align__(16) char Bs[BN*128];
  const int m0 = blockIdx.x<<7, n0 = blockIdx.y*BN;
  const int tid = threadIdx.x, lane = tid&63, wv = tid>>6;
  const int wm = wv>>1, wn = wv&1, l15 = lane&15, g4 = lane>>4;

  f32x4 acc[4][NT] = {};

  #pragma unroll 1
  for (int kt=0; kt<1024; kt+=64){
    __syncthreads();
    stage_bf16<128>(ctx + (size_t)m0*1024 + kt, 1024, As, wv, lane);
    stage_bf16<BN> (wob + (size_t)n0*1024 + kt, 1024, Bs, wv, lane);
    __syncthreads();

    #pragma unroll
    for (int kb=0;kb<64;kb+=32){
      const int kcol = kb + (g4<<3);
      bf16x8 af[4], bf_[NT];
      #pragma unroll
      for (int t=0;t<4;++t)
        af[t] = frag_bf16(As, (wm<<6) + (t<<4) + l15, kcol);
      #pragma unroll
      for (int t=0;t<NT;++t)
        bf_[t] = frag_bf16(Bs, wn*(BN>>1) + (t<<4) + l15, kcol);
      #pragma unroll
      for (int mt=0;mt<4;++mt)
        #pragma unroll
        for (int nt=0;nt<NT;++nt)
          acc[mt][nt] = MFMA(af[mt], bf_[nt], acc[mt][nt]);
    }
  }

  #pragma unroll
  for (int nt=0;nt<NT;++nt){
    const int col = n0 + wn*(BN>>1) + (nt<<4) + l15;
    const float bvn = bo[col];
    #pragma unroll
    for (int mt=0;mt<4;++mt){
      const int mb = m0 + (wm<<6) + (mt<<4) + (g4<<2);
      f32x4 a = acc[mt][nt];
      #pragma unroll
      for (int j=0;j<4;++j)
        of[(size_t)(mb+j)*1024 + col] = a[j] + bvn;
    }
  }
}

// ---------------- flash attention over COMPACTED keys ----------------
// qp bf16 [B*S,E]; kp bf16 [B*S,E] compact rows; vt bf16 [E,B*S] compact cols.
// cnts[b] = live keys. Tail slots -> -1e30 bias (exp2 -> exact 0).
__global__ __launch_bounds__(256) void attn_k(
    const u16* __restrict__ qp, const u16* __restrict__ kp, const u16* __restrict__ vt,
    const int* __restrict__ cnts, u16* __restrict__ ctx)
{
  const int bid = blockIdx.x;
  const int wg  = (bid&7)*64 + (bid>>3);     // XCD-chunked (512 = 8*64, bijective)
  const int qt = wg&7, h = (wg>>3)&15, b = wg>>7;

  __shared__ __align__(16) u16 Qs[128*64];    // 16KB
  __shared__ __align__(16) u16 Ks[2][64*64];  // 16KB
  __shared__ __align__(16) u16 Vs[2][64*64];  // 16KB (rows=d, cols=key)
  __shared__ __align__(16) u16 Ps[4*32*64];   // 16KB per-wave P

  const int tid = threadIdx.x, lane = tid&63, wv = tid>>6;
  const int hc = h<<6, l15 = lane&15;
  const float C2 = 0.18033688011112042f;      // 0.125 * log2(e)

  const int cnt = cnts[b];
  const int ntiles = (cnt + 63) >> 6;

  { // stage Q (128 x 64)
    const u16* Qg = qp + ((size_t)((b<<10) + (qt<<7)))*1024 + hc;
    #pragma unroll
    for (int i=0;i<4;++i){
      const int r0 = (wv<<5) + (i<<3);
      const int row = r0 + (lane>>3);
      const int c = ((lane&7) ^ (row&7)) << 3;
      gl16(Qg + (size_t)row*1024 + c, (char*)Qs + (r0<<7));
    }
  }

  const u16* Kg = kp + ((size_t)(b<<10))*1024 + hc;
  const u16* Vg = vt + ((size_t)hc)*4096 + (b<<10);

  auto stageKV = [&](int kt2, int bi){
    #pragma unroll
    for (int i=0;i<2;++i){
      const int r0 = (wv<<4) + (i<<3);
      const int row = r0 + (lane>>3);
      const int c = ((lane&7) ^ (row&7)) << 3;
      gl16(Kg + (size_t)((kt2<<6) + row)*1024 + c, (char*)Ks[bi] + (r0<<7));
      gl16(Vg + (size_t)row*4096 + (kt2<<6) + c,  (char*)Vs[bi] + (r0<<7));
    }
  };
  stageKV(0, 0);
  __syncthreads();

  f32x4 o[2][4] = {};
  float lr[2][4] = {};
  u16* Pw = Ps + (wv<<11);
  int cur = 0;

  #pragma unroll 1
  for (int kt=0; kt<ntiles; ++kt){
    if (kt+1 < ntiles) stageKV(kt+1, cur^1);
    const char* Kc = (const char*)Ks[cur];
    const char* Vc = (const char*)Vs[cur];

    // S = Q K^T  (2 q-subtiles x 4 key-subtiles)
    f32x4 sc[2][4] = {};
    #pragma unroll
    for (int kb=0;kb<64;kb+=32){
      const int kcol = kb + ((lane>>4)<<3);
      bf16x8 kf[4];
      #pragma unroll
      for (int nt=0;nt<4;++nt) kf[nt] = frag_bf16(Kc, (nt<<4)+l15, kcol);
      bf16x8 aq0 = frag_bf16((const char*)Qs, (wv<<5)+l15, kcol);
      bf16x8 aq1 = frag_bf16((const char*)Qs, (wv<<5)+16+l15, kcol);
      __builtin_amdgcn_s_setprio(1);
      #pragma unroll
      for (int nt=0;nt<4;++nt) sc[0][nt] = MFMA(aq0, kf[nt], sc[0][nt]);
      #pragma unroll
      for (int nt=0;nt<4;++nt) sc[1][nt] = MFMA(aq1, kf[nt], sc[1][nt]);
      __builtin_amdgcn_s_setprio(0);
    }

    // p = exp2(s*C2 + tailbias); slots >= cnt -> exact 0
    float bv4[4];
    #pragma unroll
    for (int nt=0;nt<4;++nt)
      bv4[nt] = ((kt<<6)+(nt<<4)+l15 < cnt) ? 0.f : -1e30f;
    #pragma unroll
    for (int sub=0;sub<2;++sub)
      #pragma unroll
      for (int nt=0;nt<4;++nt){
        f32x4 s = sc[sub][nt];
        #pragma unroll
        for (int j=0;j<4;++j){
          const float p = __builtin_amdgcn_exp2f(fmaf(s[j], C2, bv4[nt]));
          lr[sub][j] += p;
          *(u16*)((char*)Pw + swz((sub<<4)+((lane>>4)<<2)+j, (nt<<4)+l15)) = f2bf(p);
        }
      }
    asm volatile("s_waitcnt lgkmcnt(0)" ::: "memory");
    __builtin_amdgcn_sched_barrier(0);

    // O += P V
    #pragma unroll
    for (int kb=0;kb<64;kb+=32){
      const int kcol = kb + ((lane>>4)<<3);
      bf16x8 vf[4];
      #pragma unroll
      for (int nt=0;nt<4;++nt) vf[nt] = frag_bf16(Vc, (nt<<4)+l15, kcol);
      bf16x8 pa0 = frag_bf16((const char*)Pw, l15, kcol);
      bf16x8 pa1 = frag_bf16((const char*)Pw, 16+l15, kcol);
      __builtin_amdgcn_s_setprio(1);
      #pragma unroll
      for (int nt=0;nt<4;++nt) o[0][nt] = MFMA(pa0, vf[nt], o[0][nt]);
      #pragma unroll
      for (int nt=0;nt<4;++nt) o[1][nt] = MFMA(pa1, vf[nt], o[1][nt]);
      __builtin_amdgcn_s_setprio(0);
    }
    __syncthreads();
    cur ^= 1;
  }

  // epilogue: deferred row-sum reduce, normalize, write
  #pragma unroll
  for (int sub=0;sub<2;++sub)
    #pragma unroll
    for (int j=0;j<4;++j){
      float s = lr[sub][j];
      s += __shfl_xor(s,1); s += __shfl_xor(s,2);
      s += __shfl_xor(s,4); s += __shfl_xor(s,8);
      const float inv = 1.f / fmaxf(s, 1e-30f);
      const int row = (qt<<7) + (wv<<5) + (sub<<4) + ((lane>>4)<<2) + j;
      u16* crow = ctx + ((size_t)((b<<10)+row))*1024 + hc;
      #pragma unroll
      for (int nt=0;nt<4;++nt)
        crow[(nt<<4)+l15] = f2bf(o[sub][nt][j]*inv);
    }
}

extern "C" void kernel_launch(void* const* d_in, const int* in_sizes, int n_in,
                              void* d_out, int out_size, void* d_ws, size_t ws_size,
                              hipStream_t stream) {
  const float* q    = (const float*)d_in[0];
  const float* k    = (const float*)d_in[1];
  const float* v    = (const float*)d_in[2];
  const int*   mask = (const int*)  d_in[3];
  const float* Wq   = (const float*)d_in[4];
  const float* bq   = (const float*)d_in[5];
  const float* Wk   = (const float*)d_in[6];
  const float* bk   = (const float*)d_in[7];
  const float* Wo   = (const float*)d_in[8];
  const float* bo   = (const float*)d_in[9];
  float* out = (float*)d_out;

  // ws layout: wqb 2M | wkb 2M | wob 2M | qb 8M | kb 8M | vb 8M | qp 8M | kp 8M
  //            | vt 8M | ctx 8M | scat 16K | cnts
  char* ws = (char*)d_ws;
  u16* wqb  = (u16*)(ws);
  u16* wkb  = (u16*)(ws +  2097152);
  u16* wob  = (u16*)(ws +  4194304);
  u16* qb   = (u16*)(ws +  6291456);
  u16* kb   = (u16*)(ws + 14680064);
  u16* vb   = (u16*)(ws + 23068672);
  u16* qp   = (u16*)(ws + 31457280);
  u16* kp   = (u16*)(ws + 39845888);
  u16* vtb  = (u16*)(ws + 48234496);
  u16* ctxb = (u16*)(ws + 56623104);
  int* scat = (int*)(ws + 65011712);
  int* cnts = (int*)(ws + 65028096);

  dim3 blk(256);
  prep_k<<<7684, blk, 0, stream>>>(Wq, Wk, Wo, q, k, v, wqb, mask, scat, cnts);
  proj_k<<<768, blk, 0, stream>>>(qb, kb, vb, wqb, wkb, bq, bk, qp, kp, vtb, scat);
  attn_k<<<512, blk, 0, stream>>>(qp, kp, vtb, cnts, ctxb);
  oproj_k<<<dim3(32,16), blk, 0, stream>>>(ctxb, wob, bo, out);
}

// Round 15
// 84.544 us; speedup vs baseline: 1.2931x; 1.0686x over previous
//
#include <hip/hip_runtime.h>

typedef unsigned short u16;
typedef unsigned int   u32;
typedef __attribute__((ext_vector_type(8))) short bf16x8;
typedef __attribute__((ext_vector_type(4))) float f32x4;
typedef __attribute__((ext_vector_type(4))) u32   u32x4;

#define MFMA(a,b,c) __builtin_amdgcn_mfma_f32_16x16x32_bf16(a,b,c,0,0,0)

// B=4, S=1024, E=1024, H=16, D=64; M = B*S = 4096.

__device__ __forceinline__ u32 cvtpk(float lo, float hi){
  u32 r; asm("v_cvt_pk_bf16_f32 %0, %1, %2" : "=v"(r) : "v"(lo), "v"(hi)); return r;
}
__device__ __forceinline__ u16 f2bf(float f){ return (u16)cvtpk(f,f); }
__device__ __forceinline__ bf16x8 cvt8(f32x4 lo, f32x4 hi){
  u32x4 u;
  u.x = cvtpk(lo[0],lo[1]); u.y = cvtpk(lo[2],lo[3]);
  u.z = cvtpk(hi[0],hi[1]); u.w = cvtpk(hi[2],hi[3]);
  return *(bf16x8*)&u;
}

// XOR swizzle for [row][64 bf16] LDS tiles (128B rows). BYTE offset.
__device__ __forceinline__ int swz(int row, int col){
  return (((row<<6) + col)<<1) ^ ((row&7)<<4);
}

// async global->LDS, 16B/lane; LDS dest wave-uniform (HW adds lane*16)
__device__ __forceinline__ void gl16(const void* g, void* l){
  __builtin_amdgcn_global_load_lds(
      (const __attribute__((address_space(1))) u32*)g,
      (__attribute__((address_space(3))) u32*)l, 16, 0, 0);
}

// stage ROWSx64 bf16 tile via global_load_lds; source-side swizzle ^(row&7).
template<int ROWS>
__device__ __forceinline__ void stage_bf16(const u16* g, size_t ldg, char* lds, int wv, int lane){
  #pragma unroll
  for (int i=0;i<ROWS/32;++i){
    const int r0 = wv*(ROWS/4) + (i<<3);
    const int row = r0 + (lane>>3);
    const int c = ((lane&7) ^ (row&7)) << 3;
    gl16(g + (size_t)row*ldg + c, lds + (r0<<7));
  }
}

__device__ __forceinline__ bf16x8 frag_bf16(const char* lds, int row, int kcol){
  return *(const bf16x8*)(lds + swz(row,kcol));
}

// ---------------- cvtx + mask-compaction fused ----------------
// blocks 0..7679: fp32->bf16 convert Wq|Wk|Wo|q|k|v -> contiguous bf16 region.
// blocks 7680..7683: per-batch prefix-sum -> gidx[b][slot]=orig row (0 for pads), cnts[b].
__global__ __launch_bounds__(256) void prep_k(
    const float* __restrict__ wq, const float* __restrict__ wk, const float* __restrict__ wo,
    const float* __restrict__ q,  const float* __restrict__ k,  const float* __restrict__ v,
    u16* __restrict__ out,
    const int* __restrict__ mask, int* __restrict__ gidx, int* __restrict__ cnts)
{
  const int tid = threadIdx.x;
  if (blockIdx.x < 7680){
    const size_t i8 = (((size_t)blockIdx.x<<8) + tid) << 3;
    const float* src;
    if      (i8 <  1048576u) src = wq + i8;
    else if (i8 <  2097152u) src = wk + (i8 - 1048576u);
    else if (i8 <  3145728u) src = wo + (i8 - 2097152u);
    else if (i8 <  7340032u) src = q  + (i8 - 3145728u);
    else if (i8 < 11534336u) src = k  + (i8 - 7340032u);
    else                     src = v  + (i8 - 11534336u);
    f32x4 lo = *(const f32x4*)src, hi = *(const f32x4*)(src+4);
    *(bf16x8*)(out + i8) = cvt8(lo, hi);
  } else {
    const int b = blockIdx.x - 7680, lane = tid&63, wv = tid>>6;
    __shared__ int wsum[4];
    int4 z4; z4.x=0; z4.y=0; z4.z=0; z4.w=0;
    *(int4*)(gidx + (b<<10) + (tid<<2)) = z4;          // init pads (ordered by barrier below)
    const int4 m = *(const int4*)(mask + (b<<10) + (tid<<2));
    const int c0 = (m.x!=0)+(m.y!=0)+(m.z!=0)+(m.w!=0);
    int pre = c0;
    #pragma unroll
    for (int i=1;i<64;i<<=1){
      int t = __shfl_up(pre, i);
      if (lane >= i) pre += t;
    }
    if (lane==63) wsum[wv] = pre;
    __syncthreads();
    int base = pre - c0;
    #pragma unroll
    for (int w=0;w<4;++w) if (w<wv) base += wsum[w];
    int p = base;
    const int s0 = tid<<2;
    if (m.x) gidx[(b<<10) + p++] = s0;
    if (m.y) gidx[(b<<10) + p++] = s0+1;
    if (m.z) gidx[(b<<10) + p++] = s0+2;
    if (m.w) gidx[(b<<10) + p++] = s0+3;
    if (tid==255) cnts[b] = p;
  }
}

// ---------------- projection GEMM body (m97 form, 128x128, optional A/B row-gather) ------
// All pointers pre-offset: Aa/Bb = tile (dense) or batch base (gather, gA/gB tile-local),
// bias pre-offset (V=0: +n0, V=1: +m0), outb = tile output start.
// V=0: out row-major stride 1024, bias[n]. V=1: out vt stride 4096, bias[m].
template<int V, bool GA, bool GB>
__device__ __forceinline__ void proj_body(
    const u16* __restrict__ Aa, const u16* __restrict__ Bb,
    const int* __restrict__ gA, const int* __restrict__ gB,
    const float* __restrict__ bias, u16* __restrict__ outb,
    char* As, char* Bs)
{
  const int tid = threadIdx.x, lane = tid&63, wv = tid>>6;
  const int wm = wv>>1, wn = wv&1, l15 = lane&15, g4 = lane>>4;

  int growA[4], growB[4];
  if (GA){
    #pragma unroll
    for (int i=0;i<4;++i) growA[i] = gA[(wv<<5)+(i<<3)+(lane>>3)] & 1023;
  }
  if (GB){
    #pragma unroll
    for (int i=0;i<4;++i) growB[i] = gB[(wv<<5)+(i<<3)+(lane>>3)] & 1023;
  }

  f32x4 acc[4][4] = {};

  #pragma unroll 1
  for (int kt=0; kt<1024; kt+=64){
    __syncthreads();
    #pragma unroll
    for (int i=0;i<4;++i){
      const int r0 = (wv<<5)+(i<<3), row = r0+(lane>>3);
      const int c = ((lane&7)^(row&7))<<3;
      const u16* srcA = GA ? Aa + (size_t)growA[i]*1024 + kt + c
                           : Aa + (size_t)row*1024 + kt + c;
      gl16(srcA, As + (r0<<7));
      const u16* srcB = GB ? Bb + (size_t)growB[i]*1024 + kt + c
                           : Bb + (size_t)row*1024 + kt + c;
      gl16(srcB, Bs + (r0<<7));
    }
    __syncthreads();

    #pragma unroll
    for (int kb=0;kb<64;kb+=32){
      const int kcol = kb + (g4<<3);
      bf16x8 af[4], bf_[4];
      #pragma unroll
      for (int t=0;t<4;++t)
        af[t] = frag_bf16(As, (wm<<6) + (t<<4) + l15, kcol);
      #pragma unroll
      for (int t=0;t<4;++t)
        bf_[t] = frag_bf16(Bs, (wn<<6) + (t<<4) + l15, kcol);
      #pragma unroll
      for (int mt=0;mt<4;++mt)
        #pragma unroll
        for (int nt=0;nt<4;++nt)
          acc[mt][nt] = MFMA(af[mt], bf_[nt], acc[mt][nt]);
    }
  }

  // epilogue (dense writes; pad slots hold garbage that attention zeroes)
  f32x4 bmv[4];
  if (V==1){
    #pragma unroll
    for (int mt=0;mt<4;++mt)
      bmv[mt] = *(const f32x4*)(bias + (wm<<6) + (mt<<4) + (g4<<2));
  }
  #pragma unroll
  for (int nt=0;nt<4;++nt){
    const int col = (wn<<6) + (nt<<4) + l15;
    const float bvn = (V==1) ? 0.f : bias[col];
    #pragma unroll
    for (int mt=0;mt<4;++mt){
      f32x4 a = acc[mt][nt];
      #pragma unroll
      for (int j=0;j<4;++j){
        const int ml = (wm<<6) + (mt<<4) + (g4<<2) + j;
        const float val = a[j] + ((V==1) ? bmv[mt][j] : bvn);
        if (V==1) outb[(size_t)ml*4096 + col] = f2bf(val);
        else      outb[(size_t)ml*1024 + col] = f2bf(val);
      }
    }
  }
}

// ---------------- all three projections in ONE launch (768 blocks, all 128x128) ----------
// bid 0..255:   q-proj dense
// bid 256..511: k-proj, A rows gathered by gidx, dense compact-row writes; dead tiles exit
// bid 512..767: v^T-proj, B rows gathered by gidx, dense compact-col writes; dead tiles exit
__global__ __launch_bounds__(256,4) void proj_k(
    const u16* __restrict__ qb, const u16* __restrict__ kb, const u16* __restrict__ vb,
    const u16* __restrict__ wqb, const u16* __restrict__ wkb,
    const float* __restrict__ bq, const float* __restrict__ bk,
    u16* __restrict__ qp, u16* __restrict__ kp, u16* __restrict__ vt,
    const int* __restrict__ gidx, const int* __restrict__ cnts)
{
  __shared__ __align__(16) char As[16384];
  __shared__ __align__(16) char Bs[16384];
  const int bid = blockIdx.x;
  if (bid < 256){
    const int m0 = (bid&31)<<7, n0 = ((bid>>5)&7)<<7;
    proj_body<0,false,false>(qb + (size_t)m0*1024, wqb + (size_t)n0*1024, nullptr, nullptr,
                             bq + n0, qp + (size_t)m0*1024 + n0, As, Bs);
  } else if (bid < 512){
    const int local = bid-256;
    const int m0 = (local&31)<<7, n0 = ((local>>5)&7)<<7;
    const int b = m0>>10, mloc = m0&1023;
    if (mloc >= cnts[b]) return;                       // whole tile masked away
    proj_body<0,true,false>(kb + ((size_t)(b<<10))*1024, wkb + (size_t)n0*1024,
                            gidx + (b<<10) + mloc, nullptr,
                            bk + n0, kp + ((size_t)((b<<10)+mloc))*1024 + n0, As, Bs);
  } else {
    const int local = bid-512;
    const int m0 = (local&7)<<7, n0 = (local>>3)<<7;   // m over E=1024, n over B*S=4096
    const int b = n0>>10, nloc = n0&1023;
    if (nloc >= cnts[b]) return;
    proj_body<1,false,true>(wkb + (size_t)m0*1024, vb + ((size_t)(b<<10))*1024,
                            nullptr, gidx + (b<<10) + nloc,
                            bk + m0, vt + (size_t)m0*4096 + (b<<10) + nloc, As, Bs);
  }
}

// ---------------- output projection: out = ctx @ Wo^T + bo (f32 out) ----------------
__global__ __launch_bounds__(256,4) void oproj_k(
    const u16* __restrict__ ctx, const u16* __restrict__ wob,
    const float* __restrict__ bo, float* __restrict__ of)
{
  constexpr int BN = 64, NT = 2;
  __shared__ __align__(16) char As[16384];
  __shared__ __align__(16) char Bs[BN*128];
  const int m0 = blockIdx.x<<7, n0 = blockIdx.y*BN;
  const int tid = threadIdx.x, lane = tid&63, wv = tid>>6;
  const int wm = wv>>1, wn = wv&1, l15 = lane&15, g4 = lane>>4;

  f32x4 acc[4][NT] = {};

  #pragma unroll 1
  for (int kt=0; kt<1024; kt+=64){
    __syncthreads();
    stage_bf16<128>(ctx + (size_t)m0*1024 + kt, 1024, As, wv, lane);
    stage_bf16<BN> (wob + (size_t)n0*1024 + kt, 1024, Bs, wv, lane);
    __syncthreads();

    #pragma unroll
    for (int kb=0;kb<64;kb+=32){
      const int kcol = kb + (g4<<3);
      bf16x8 af[4], bf_[NT];
      #pragma unroll
      for (int t=0;t<4;++t)
        af[t] = frag_bf16(As, (wm<<6) + (t<<4) + l15, kcol);
      #pragma unroll
      for (int t=0;t<NT;++t)
        bf_[t] = frag_bf16(Bs, wn*(BN>>1) + (t<<4) + l15, kcol);
      #pragma unroll
      for (int mt=0;mt<4;++mt)
        #pragma unroll
        for (int nt=0;nt<NT;++nt)
          acc[mt][nt] = MFMA(af[mt], bf_[nt], acc[mt][nt]);
    }
  }

  #pragma unroll
  for (int nt=0;nt<NT;++nt){
    const int col = n0 + wn*(BN>>1) + (nt<<4) + l15;
    const float bvn = bo[col];
    #pragma unroll
    for (int mt=0;mt<4;++mt){
      const int mb = m0 + (wm<<6) + (mt<<4) + (g4<<2);
      f32x4 a = acc[mt][nt];
      #pragma unroll
      for (int j=0;j<4;++j)
        of[(size_t)(mb+j)*1024 + col] = a[j] + bvn;
    }
  }
}

// ---------------- flash attention over COMPACTED keys ----------------
// qp bf16 [B*S,E]; kp bf16 [B*S,E] compact rows; vt bf16 [E,B*S] compact cols.
// cnts[b] = live keys. Tail slots -> -1e30 bias (exp2 -> exact 0).
__global__ __launch_bounds__(256) void attn_k(
    const u16* __restrict__ qp, const u16* __restrict__ kp, const u16* __restrict__ vt,
    const int* __restrict__ cnts, u16* __restrict__ ctx)
{
  const int bid = blockIdx.x;
  const int wg  = (bid&7)*64 + (bid>>3);     // XCD-chunked (512 = 8*64, bijective)
  const int qt = wg&7, h = (wg>>3)&15, b = wg>>7;

  __shared__ __align__(16) u16 Qs[128*64];    // 16KB
  __shared__ __align__(16) u16 Ks[2][64*64];  // 16KB
  __shared__ __align__(16) u16 Vs[2][64*64];  // 16KB (rows=d, cols=key)
  __shared__ __align__(16) u16 Ps[4*32*64];   // 16KB per-wave P

  const int tid = threadIdx.x, lane = tid&63, wv = tid>>6;
  const int hc = h<<6, l15 = lane&15;
  const float C2 = 0.18033688011112042f;      // 0.125 * log2(e)

  const int cnt = cnts[b];
  const int ntiles = (cnt + 63) >> 6;

  { // stage Q (128 x 64)
    const u16* Qg = qp + ((size_t)((b<<10) + (qt<<7)))*1024 + hc;
    #pragma unroll
    for (int i=0;i<4;++i){
      const int r0 = (wv<<5) + (i<<3);
      const int row = r0 + (lane>>3);
      const int c = ((lane&7) ^ (row&7)) << 3;
      gl16(Qg + (size_t)row*1024 + c, (char*)Qs + (r0<<7));
    }
  }

  const u16* Kg = kp + ((size_t)(b<<10))*1024 + hc;
  const u16* Vg = vt + ((size_t)hc)*4096 + (b<<10);

  auto stageKV = [&](int kt2, int bi){
    #pragma unroll
    for (int i=0;i<2;++i){
      const int r0 = (wv<<4) + (i<<3);
      const int row = r0 + (lane>>3);
      const int c = ((lane&7) ^ (row&7)) << 3;
      gl16(Kg + (size_t)((kt2<<6) + row)*1024 + c, (char*)Ks[bi] + (r0<<7));
      gl16(Vg + (size_t)row*4096 + (kt2<<6) + c,  (char*)Vs[bi] + (r0<<7));
    }
  };
  stageKV(0, 0);
  __syncthreads();

  f32x4 o[2][4] = {};
  float lr[2][4] = {};
  u16* Pw = Ps + (wv<<11);
  int cur = 0;

  #pragma unroll 1
  for (int kt=0; kt<ntiles; ++kt){
    if (kt+1 < ntiles) stageKV(kt+1, cur^1);
    const char* Kc = (const char*)Ks[cur];
    const char* Vc = (const char*)Vs[cur];

    // S = Q K^T  (2 q-subtiles x 4 key-subtiles)
    f32x4 sc[2][4] = {};
    #pragma unroll
    for (int kb=0;kb<64;kb+=32){
      const int kcol = kb + ((lane>>4)<<3);
      bf16x8 kf[4];
      #pragma unroll
      for (int nt=0;nt<4;++nt) kf[nt] = frag_bf16(Kc, (nt<<4)+l15, kcol);
      bf16x8 aq0 = frag_bf16((const char*)Qs, (wv<<5)+l15, kcol);
      bf16x8 aq1 = frag_bf16((const char*)Qs, (wv<<5)+16+l15, kcol);
      __builtin_amdgcn_s_setprio(1);
      #pragma unroll
      for (int nt=0;nt<4;++nt) sc[0][nt] = MFMA(aq0, kf[nt], sc[0][nt]);
      #pragma unroll
      for (int nt=0;nt<4;++nt) sc[1][nt] = MFMA(aq1, kf[nt], sc[1][nt]);
      __builtin_amdgcn_s_setprio(0);
    }

    // p = exp2(s*C2 + tailbias); slots >= cnt -> exact 0
    float bv4[4];
    #pragma unroll
    for (int nt=0;nt<4;++nt)
      bv4[nt] = ((kt<<6)+(nt<<4)+l15 < cnt) ? 0.f : -1e30f;
    #pragma unroll
    for (int sub=0;sub<2;++sub)
      #pragma unroll
      for (int nt=0;nt<4;++nt){
        f32x4 s = sc[sub][nt];
        #pragma unroll
        for (int j=0;j<4;++j){
          const float p = __builtin_amdgcn_exp2f(fmaf(s[j], C2, bv4[nt]));
          lr[sub][j] += p;
          *(u16*)((char*)Pw + swz((sub<<4)+((lane>>4)<<2)+j, (nt<<4)+l15)) = f2bf(p);
        }
      }
    asm volatile("s_waitcnt lgkmcnt(0)" ::: "memory");
    __builtin_amdgcn_sched_barrier(0);

    // O += P V
    #pragma unroll
    for (int kb=0;kb<64;kb+=32){
      const int kcol = kb + ((lane>>4)<<3);
      bf16x8 vf[4];
      #pragma unroll
      for (int nt=0;nt<4;++nt) vf[nt] = frag_bf16(Vc, (nt<<4)+l15, kcol);
      bf16x8 pa0 = frag_bf16((const char*)Pw, l15, kcol);
      bf16x8 pa1 = frag_bf16((const char*)Pw, 16+l15, kcol);
      __builtin_amdgcn_s_setprio(1);
      #pragma unroll
      for (int nt=0;nt<4;++nt) o[0][nt] = MFMA(pa0, vf[nt], o[0][nt]);
      #pragma unroll
      for (int nt=0;nt<4;++nt) o[1][nt] = MFMA(pa1, vf[nt], o[1][nt]);
      __builtin_amdgcn_s_setprio(0);
    }
    __syncthreads();
    cur ^= 1;
  }

  // epilogue: deferred row-sum reduce, normalize, write
  #pragma unroll
  for (int sub=0;sub<2;++sub)
    #pragma unroll
    for (int j=0;j<4;++j){
      float s = lr[sub][j];
      s += __shfl_xor(s,1); s += __shfl_xor(s,2);
      s += __shfl_xor(s,4); s += __shfl_xor(s,8);
      const float inv = 1.f / fmaxf(s, 1e-30f);
      const int row = (qt<<7) + (wv<<5) + (sub<<4) + ((lane>>4)<<2) + j;
      u16* crow = ctx + ((size_t)((b<<10)+row))*1024 + hc;
      #pragma unroll
      for (int nt=0;nt<4;++nt)
        crow[(nt<<4)+l15] = f2bf(o[sub][nt][j]*inv);
    }
}

extern "C" void kernel_launch(void* const* d_in, const int* in_sizes, int n_in,
                              void* d_out, int out_size, void* d_ws, size_t ws_size,
                              hipStream_t stream) {
  const float* q    = (const float*)d_in[0];
  const float* k    = (const float*)d_in[1];
  const float* v    = (const float*)d_in[2];
  const int*   mask = (const int*)  d_in[3];
  const float* Wq   = (const float*)d_in[4];
  const float* bq   = (const float*)d_in[5];
  const float* Wk   = (const float*)d_in[6];
  const float* bk   = (const float*)d_in[7];
  const float* Wo   = (const float*)d_in[8];
  const float* bo   = (const float*)d_in[9];
  float* out = (float*)d_out;

  // ws layout: wqb 2M | wkb 2M | wob 2M | qb 8M | kb 8M | vb 8M | qp 8M | kp 8M
  //            | vt 8M | ctx 8M | gidx 16K | cnts
  char* ws = (char*)d_ws;
  u16* wqb  = (u16*)(ws);
  u16* wkb  = (u16*)(ws +  2097152);
  u16* wob  = (u16*)(ws +  4194304);
  u16* qb   = (u16*)(ws +  6291456);
  u16* kb   = (u16*)(ws + 14680064);
  u16* vb   = (u16*)(ws + 23068672);
  u16* qp   = (u16*)(ws + 31457280);
  u16* kp   = (u16*)(ws + 39845888);
  u16* vtb  = (u16*)(ws + 48234496);
  u16* ctxb = (u16*)(ws + 56623104);
  int* gidx = (int*)(ws + 65011712);
  int* cnts = (int*)(ws + 65028096);

  dim3 blk(256);
  prep_k<<<7684, blk, 0, stream>>>(Wq, Wk, Wo, q, k, v, wqb, mask, gidx, cnts);
  proj_k<<<768, blk, 0, stream>>>(qb, kb, vb, wqb, wkb, bq, bk, qp, kp, vtb, gidx, cnts);
  attn_k<<<512, blk, 0, stream>>>(qp, kp, vtb, cnts, ctxb);
  oproj_k<<<dim3(32,16), blk, 0, stream>>>(ctxb, wob, bo, out);
}

// Round 16
// 81.226 us; speedup vs baseline: 1.3459x; 1.0408x over previous
//
#include <hip/hip_runtime.h>

typedef unsigned short u16;
typedef unsigned int   u32;
typedef __attribute__((ext_vector_type(8))) short bf16x8;
typedef __attribute__((ext_vector_type(4))) float f32x4;
typedef __attribute__((ext_vector_type(4))) u32   u32x4;

#define MFMA(a,b,c) __builtin_amdgcn_mfma_f32_16x16x32_bf16(a,b,c,0,0,0)

// B=4, S=1024, E=1024, H=16, D=64; M = B*S = 4096.

__device__ __forceinline__ u32 cvtpk(float lo, float hi){
  u32 r; asm("v_cvt_pk_bf16_f32 %0, %1, %2" : "=v"(r) : "v"(lo), "v"(hi)); return r;
}
__device__ __forceinline__ u16 f2bf(float f){ return (u16)cvtpk(f,f); }
__device__ __forceinline__ bf16x8 cvt8(f32x4 lo, f32x4 hi){
  u32x4 u;
  u.x = cvtpk(lo[0],lo[1]); u.y = cvtpk(lo[2],lo[3]);
  u.z = cvtpk(hi[0],hi[1]); u.w = cvtpk(hi[2],hi[3]);
  return *(bf16x8*)&u;
}

// XOR swizzle for [row][64 bf16] LDS tiles (128B rows). BYTE offset.
__device__ __forceinline__ int swz(int row, int col){
  return (((row<<6) + col)<<1) ^ ((row&7)<<4);
}

// async global->LDS, 16B/lane; LDS dest wave-uniform (HW adds lane*16)
__device__ __forceinline__ void gl16(const void* g, void* l){
  __builtin_amdgcn_global_load_lds(
      (const __attribute__((address_space(1))) u32*)g,
      (__attribute__((address_space(3))) u32*)l, 16, 0, 0);
}

// stage ROWSx64 bf16 tile via global_load_lds; source-side swizzle ^(row&7).
template<int ROWS>
__device__ __forceinline__ void stage_bf16(const u16* g, size_t ldg, char* lds, int wv, int lane){
  #pragma unroll
  for (int i=0;i<ROWS/32;++i){
    const int r0 = wv*(ROWS/4) + (i<<3);
    const int row = r0 + (lane>>3);
    const int c = ((lane&7) ^ (row&7)) << 3;
    gl16(g + (size_t)row*ldg + c, lds + (r0<<7));
  }
}

__device__ __forceinline__ bf16x8 frag_bf16(const char* lds, int row, int kcol){
  return *(const bf16x8*)(lds + swz(row,kcol));
}

// ---------------- cvtx + mask-compaction fused ----------------
// blocks 0..7679: fp32->bf16 convert Wq|Wk|Wo|q|k|v -> contiguous bf16 region.
//   k/v input rows that are masked-out are SKIPPED (never gathered downstream;
//   pad-slot garbage is provably zeroed by attention's tail bias).
// blocks 7680..7683: per-batch prefix-sum -> gidx[b][slot]=orig row (0 pads), cnts[b].
__global__ __launch_bounds__(256) void prep_k(
    const float* __restrict__ wq, const float* __restrict__ wk, const float* __restrict__ wo,
    const float* __restrict__ q,  const float* __restrict__ k,  const float* __restrict__ v,
    u16* __restrict__ out,
    const int* __restrict__ mask, int* __restrict__ gidx, int* __restrict__ cnts)
{
  const int tid = threadIdx.x;
  if (blockIdx.x < 7680){
    const size_t i8 = (((size_t)blockIdx.x<<8) + tid) << 3;
    const float* src;
    if      (i8 <  1048576u) src = wq + i8;
    else if (i8 <  2097152u) src = wk + (i8 - 1048576u);
    else if (i8 <  3145728u) src = wo + (i8 - 2097152u);
    else if (i8 <  7340032u) src = q  + (i8 - 3145728u);
    else if (i8 < 11534336u){
      const size_t off = i8 - 7340032u;
      if (!mask[off>>10]) return;        // row = b*1024+s; mask is [B,S] flat
      src = k + off;
    } else {
      const size_t off = i8 - 11534336u;
      if (!mask[off>>10]) return;
      src = v + off;
    }
    f32x4 lo = *(const f32x4*)src, hi = *(const f32x4*)(src+4);
    *(bf16x8*)(out + i8) = cvt8(lo, hi);
  } else {
    const int b = blockIdx.x - 7680, lane = tid&63, wv = tid>>6;
    __shared__ int wsum[4];
    int4 z4; z4.x=0; z4.y=0; z4.z=0; z4.w=0;
    *(int4*)(gidx + (b<<10) + (tid<<2)) = z4;          // init pads
    const int4 m = *(const int4*)(mask + (b<<10) + (tid<<2));
    const int c0 = (m.x!=0)+(m.y!=0)+(m.z!=0)+(m.w!=0);
    int pre = c0;
    #pragma unroll
    for (int i=1;i<64;i<<=1){
      int t = __shfl_up(pre, i);
      if (lane >= i) pre += t;
    }
    if (lane==63) wsum[wv] = pre;
    __syncthreads();
    int base = pre - c0;
    #pragma unroll
    for (int w=0;w<4;++w) if (w<wv) base += wsum[w];
    int p = base;
    const int s0 = tid<<2;
    if (m.x) gidx[(b<<10) + p++] = s0;
    if (m.y) gidx[(b<<10) + p++] = s0+1;
    if (m.z) gidx[(b<<10) + p++] = s0+2;
    if (m.w) gidx[(b<<10) + p++] = s0+3;
    if (tid==255) cnts[b] = p;
  }
}

// ---------------- projection GEMM body (m97 form, 128x128, optional A/B row-gather) ------
template<int V, bool GA, bool GB>
__device__ __forceinline__ void proj_body(
    const u16* __restrict__ Aa, const u16* __restrict__ Bb,
    const int* __restrict__ gA, const int* __restrict__ gB,
    const float* __restrict__ bias, u16* __restrict__ outb,
    char* As, char* Bs)
{
  const int tid = threadIdx.x, lane = tid&63, wv = tid>>6;
  const int wm = wv>>1, wn = wv&1, l15 = lane&15, g4 = lane>>4;

  int growA[4], growB[4];
  if (GA){
    #pragma unroll
    for (int i=0;i<4;++i) growA[i] = gA[(wv<<5)+(i<<3)+(lane>>3)] & 1023;
  }
  if (GB){
    #pragma unroll
    for (int i=0;i<4;++i) growB[i] = gB[(wv<<5)+(i<<3)+(lane>>3)] & 1023;
  }

  f32x4 acc[4][4] = {};

  #pragma unroll 1
  for (int kt=0; kt<1024; kt+=64){
    __syncthreads();
    #pragma unroll
    for (int i=0;i<4;++i){
      const int r0 = (wv<<5)+(i<<3), row = r0+(lane>>3);
      const int c = ((lane&7)^(row&7))<<3;
      const u16* srcA = GA ? Aa + (size_t)growA[i]*1024 + kt + c
                           : Aa + (size_t)row*1024 + kt + c;
      gl16(srcA, As + (r0<<7));
      const u16* srcB = GB ? Bb + (size_t)growB[i]*1024 + kt + c
                           : Bb + (size_t)row*1024 + kt + c;
      gl16(srcB, Bs + (r0<<7));
    }
    __syncthreads();

    #pragma unroll
    for (int kb=0;kb<64;kb+=32){
      const int kcol = kb + (g4<<3);
      bf16x8 af[4], bf_[4];
      #pragma unroll
      for (int t=0;t<4;++t)
        af[t] = frag_bf16(As, (wm<<6) + (t<<4) + l15, kcol);
      #pragma unroll
      for (int t=0;t<4;++t)
        bf_[t] = frag_bf16(Bs, (wn<<6) + (t<<4) + l15, kcol);
      #pragma unroll
      for (int mt=0;mt<4;++mt)
        #pragma unroll
        for (int nt=0;nt<4;++nt)
          acc[mt][nt] = MFMA(af[mt], bf_[nt], acc[mt][nt]);
    }
  }

  f32x4 bmv[4];
  if (V==1){
    #pragma unroll
    for (int mt=0;mt<4;++mt)
      bmv[mt] = *(const f32x4*)(bias + (wm<<6) + (mt<<4) + (g4<<2));
  }
  #pragma unroll
  for (int nt=0;nt<4;++nt){
    const int col = (wn<<6) + (nt<<4) + l15;
    const float bvn = (V==1) ? 0.f : bias[col];
    #pragma unroll
    for (int mt=0;mt<4;++mt){
      f32x4 a = acc[mt][nt];
      #pragma unroll
      for (int j=0;j<4;++j){
        const int ml = (wm<<6) + (mt<<4) + (g4<<2) + j;
        const float val = a[j] + ((V==1) ? bmv[mt][j] : bvn);
        if (V==1) outb[(size_t)ml*4096 + col] = f2bf(val);
        else      outb[(size_t)ml*1024 + col] = f2bf(val);
      }
    }
  }
}

// ---------------- all three projections in ONE launch (768 blocks, all 128x128) ----------
__global__ __launch_bounds__(256,4) void proj_k(
    const u16* __restrict__ qb, const u16* __restrict__ kb, const u16* __restrict__ vb,
    const u16* __restrict__ wqb, const u16* __restrict__ wkb,
    const float* __restrict__ bq, const float* __restrict__ bk,
    u16* __restrict__ qp, u16* __restrict__ kp, u16* __restrict__ vt,
    const int* __restrict__ gidx, const int* __restrict__ cnts)
{
  __shared__ __align__(16) char As[16384];
  __shared__ __align__(16) char Bs[16384];
  const int bid = blockIdx.x;
  if (bid < 256){
    const int m0 = (bid&31)<<7, n0 = ((bid>>5)&7)<<7;
    proj_body<0,false,false>(qb + (size_t)m0*1024, wqb + (size_t)n0*1024, nullptr, nullptr,
                             bq + n0, qp + (size_t)m0*1024 + n0, As, Bs);
  } else if (bid < 512){
    const int local = bid-256;
    const int m0 = (local&31)<<7, n0 = ((local>>5)&7)<<7;
    const int b = m0>>10, mloc = m0&1023;
    if (mloc >= cnts[b]) return;
    proj_body<0,true,false>(kb + ((size_t)(b<<10))*1024, wkb + (size_t)n0*1024,
                            gidx + (b<<10) + mloc, nullptr,
                            bk + n0, kp + ((size_t)((b<<10)+mloc))*1024 + n0, As, Bs);
  } else {
    const int local = bid-512;
    const int m0 = (local&7)<<7, n0 = (local>>3)<<7;
    const int b = n0>>10, nloc = n0&1023;
    if (nloc >= cnts[b]) return;
    proj_body<1,false,true>(wkb + (size_t)m0*1024, vb + ((size_t)(b<<10))*1024,
                            nullptr, gidx + (b<<10) + nloc,
                            bk + m0, vt + (size_t)m0*4096 + (b<<10) + nloc, As, Bs);
  }
}

// ---------------- output projection: out = ctx @ Wo^T + bo (f32 out) ----------------
__global__ __launch_bounds__(256,4) void oproj_k(
    const u16* __restrict__ ctx, const u16* __restrict__ wob,
    const float* __restrict__ bo, float* __restrict__ of)
{
  constexpr int BN = 64, NT = 2;
  __shared__ __align__(16) char As[16384];
  __shared__ __align__(16) char Bs[BN*128];
  const int m0 = blockIdx.x<<7, n0 = blockIdx.y*BN;
  const int tid = threadIdx.x, lane = tid&63, wv = tid>>6;
  const int wm = wv>>1, wn = wv&1, l15 = lane&15, g4 = lane>>4;

  f32x4 acc[4][NT] = {};

  #pragma unroll 1
  for (int kt=0; kt<1024; kt+=64){
    __syncthreads();
    stage_bf16<128>(ctx + (size_t)m0*1024 + kt, 1024, As, wv, lane);
    stage_bf16<BN> (wob + (size_t)n0*1024 + kt, 1024, Bs, wv, lane);
    __syncthreads();

    #pragma unroll
    for (int kb=0;kb<64;kb+=32){
      const int kcol = kb + (g4<<3);
      bf16x8 af[4], bf_[NT];
      #pragma unroll
      for (int t=0;t<4;++t)
        af[t] = frag_bf16(As, (wm<<6) + (t<<4) + l15, kcol);
      #pragma unroll
      for (int t=0;t<NT;++t)
        bf_[t] = frag_bf16(Bs, wn*(BN>>1) + (t<<4) + l15, kcol);
      #pragma unroll
      for (int mt=0;mt<4;++mt)
        #pragma unroll
        for (int nt=0;nt<NT;++nt)
          acc[mt][nt] = MFMA(af[mt], bf_[nt], acc[mt][nt]);
    }
  }

  #pragma unroll
  for (int nt=0;nt<NT;++nt){
    const int col = n0 + wn*(BN>>1) + (nt<<4) + l15;
    const float bvn = bo[col];
    #pragma unroll
    for (int mt=0;mt<4;++mt){
      const int mb = m0 + (wm<<6) + (mt<<4) + (g4<<2);
      f32x4 a = acc[mt][nt];
      #pragma unroll
      for (int j=0;j<4;++j)
        of[(size_t)(mb+j)*1024 + col] = a[j] + bvn;
    }
  }
}

// ---------------- flash attention over COMPACTED keys (single-buffer K/V, 48KB LDS) -----
// qp bf16 [B*S,E]; kp bf16 [B*S,E] compact rows; vt bf16 [E,B*S] compact cols.
// cnts[b] = live keys. Tail slots -> -1e30 bias (exp2 -> exact 0).
__global__ __launch_bounds__(256) void attn_k(
    const u16* __restrict__ qp, const u16* __restrict__ kp, const u16* __restrict__ vt,
    const int* __restrict__ cnts, u16* __restrict__ ctx)
{
  const int bid = blockIdx.x;
  const int wg  = (bid&7)*64 + (bid>>3);     // XCD-chunked (512 = 8*64, bijective)
  const int qt = wg&7, h = (wg>>3)&15, b = wg>>7;

  __shared__ __align__(16) u16 Qs[128*64];    // 16KB
  __shared__ __align__(16) u16 Ks[64*64];     // 8KB
  __shared__ __align__(16) u16 Vs[64*64];     // 8KB (rows=d, cols=key)
  __shared__ __align__(16) u16 Ps[4*32*64];   // 16KB per-wave P

  const int tid = threadIdx.x, lane = tid&63, wv = tid>>6;
  const int hc = h<<6, l15 = lane&15;
  const float C2 = 0.18033688011112042f;      // 0.125 * log2(e)

  const int cnt = cnts[b];
  const int ntiles = (cnt + 63) >> 6;

  { // stage Q (128 x 64)
    const u16* Qg = qp + ((size_t)((b<<10) + (qt<<7)))*1024 + hc;
    #pragma unroll
    for (int i=0;i<4;++i){
      const int r0 = (wv<<5) + (i<<3);
      const int row = r0 + (lane>>3);
      const int c = ((lane&7) ^ (row&7)) << 3;
      gl16(Qg + (size_t)row*1024 + c, (char*)Qs + (r0<<7));
    }
  }

  const u16* Kg = kp + ((size_t)(b<<10))*1024 + hc;
  const u16* Vg = vt + ((size_t)hc)*4096 + (b<<10);

  f32x4 o[2][4] = {};
  float lr[2][4] = {};
  u16* Pw = Ps + (wv<<11);

  #pragma unroll 1
  for (int kt=0; kt<ntiles; ++kt){
    __syncthreads();   // previous tile's compute done -> safe to overwrite K/V
    { // stage K/V tile kt (single buffer)
      #pragma unroll
      for (int i=0;i<2;++i){
        const int r0 = (wv<<4) + (i<<3);
        const int row = r0 + (lane>>3);
        const int c = ((lane&7) ^ (row&7)) << 3;
        gl16(Kg + (size_t)((kt<<6) + row)*1024 + c, (char*)Ks + (r0<<7));
        gl16(Vg + (size_t)row*4096 + (kt<<6) + c,  (char*)Vs + (r0<<7));
      }
    }
    __syncthreads();   // staged (compiler drains vmcnt; covers Q on first iter)

    // S = Q K^T  (2 q-subtiles x 4 key-subtiles)
    f32x4 sc[2][4] = {};
    #pragma unroll
    for (int kb=0;kb<64;kb+=32){
      const int kcol = kb + ((lane>>4)<<3);
      bf16x8 kf[4];
      #pragma unroll
      for (int nt=0;nt<4;++nt) kf[nt] = frag_bf16((const char*)Ks, (nt<<4)+l15, kcol);
      bf16x8 aq0 = frag_bf16((const char*)Qs, (wv<<5)+l15, kcol);
      bf16x8 aq1 = frag_bf16((const char*)Qs, (wv<<5)+16+l15, kcol);
      __builtin_amdgcn_s_setprio(1);
      #pragma unroll
      for (int nt=0;nt<4;++nt) sc[0][nt] = MFMA(aq0, kf[nt], sc[0][nt]);
      #pragma unroll
      for (int nt=0;nt<4;++nt) sc[1][nt] = MFMA(aq1, kf[nt], sc[1][nt]);
      __builtin_amdgcn_s_setprio(0);
    }

    // p = exp2(s*C2 + tailbias); slots >= cnt -> exact 0
    float bv4[4];
    #pragma unroll
    for (int nt=0;nt<4;++nt)
      bv4[nt] = ((kt<<6)+(nt<<4)+l15 < cnt) ? 0.f : -1e30f;
    #pragma unroll
    for (int sub=0;sub<2;++sub)
      #pragma unroll
      for (int nt=0;nt<4;++nt){
        f32x4 s = sc[sub][nt];
        #pragma unroll
        for (int j=0;j<4;++j){
          const float p = __builtin_amdgcn_exp2f(fmaf(s[j], C2, bv4[nt]));
          lr[sub][j] += p;
          *(u16*)((char*)Pw + swz((sub<<4)+((lane>>4)<<2)+j, (nt<<4)+l15)) = f2bf(p);
        }
      }
    asm volatile("s_waitcnt lgkmcnt(0)" ::: "memory");
    __builtin_amdgcn_sched_barrier(0);

    // O += P V
    #pragma unroll
    for (int kb=0;kb<64;kb+=32){
      const int kcol = kb + ((lane>>4)<<3);
      bf16x8 vf[4];
      #pragma unroll
      for (int nt=0;nt<4;++nt) vf[nt] = frag_bf16((const char*)Vs, (nt<<4)+l15, kcol);
      bf16x8 pa0 = frag_bf16((const char*)Pw, l15, kcol);
      bf16x8 pa1 = frag_bf16((const char*)Pw, 16+l15, kcol);
      __builtin_amdgcn_s_setprio(1);
      #pragma unroll
      for (int nt=0;nt<4;++nt) o[0][nt] = MFMA(pa0, vf[nt], o[0][nt]);
      #pragma unroll
      for (int nt=0;nt<4;++nt) o[1][nt] = MFMA(pa1, vf[nt], o[1][nt]);
      __builtin_amdgcn_s_setprio(0);
    }
  }

  // epilogue: deferred row-sum reduce, normalize, write
  #pragma unroll
  for (int sub=0;sub<2;++sub)
    #pragma unroll
    for (int j=0;j<4;++j){
      float s = lr[sub][j];
      s += __shfl_xor(s,1); s += __shfl_xor(s,2);
      s += __shfl_xor(s,4); s += __shfl_xor(s,8);
      const float inv = 1.f / fmaxf(s, 1e-30f);
      const int row = (qt<<7) + (wv<<5) + (sub<<4) + ((lane>>4)<<2) + j;
      u16* crow = ctx + ((size_t)((b<<10)+row))*1024 + hc;
      #pragma unroll
      for (int nt=0;nt<4;++nt)
        crow[(nt<<4)+l15] = f2bf(o[sub][nt][j]*inv);
    }
}

extern "C" void kernel_launch(void* const* d_in, const int* in_sizes, int n_in,
                              void* d_out, int out_size, void* d_ws, size_t ws_size,
                              hipStream_t stream) {
  const float* q    = (const float*)d_in[0];
  const float* k    = (const float*)d_in[1];
  const float* v    = (const float*)d_in[2];
  const int*   mask = (const int*)  d_in[3];
  const float* Wq   = (const float*)d_in[4];
  const float* bq   = (const float*)d_in[5];
  const float* Wk   = (const float*)d_in[6];
  const float* bk   = (const float*)d_in[7];
  const float* Wo   = (const float*)d_in[8];
  const float* bo   = (const float*)d_in[9];
  float* out = (float*)d_out;

  // ws layout: wqb 2M | wkb 2M | wob 2M | qb 8M | kb 8M | vb 8M | qp 8M | kp 8M
  //            | vt 8M | ctx 8M | gidx 16K | cnts
  char* ws = (char*)d_ws;
  u16* wqb  = (u16*)(ws);
  u16* wkb  = (u16*)(ws +  2097152);
  u16* wob  = (u16*)(ws +  4194304);
  u16* qb   = (u16*)(ws +  6291456);
  u16* kb   = (u16*)(ws + 14680064);
  u16* vb   = (u16*)(ws + 23068672);
  u16* qp   = (u16*)(ws + 31457280);
  u16* kp   = (u16*)(ws + 39845888);
  u16* vtb  = (u16*)(ws + 48234496);
  u16* ctxb = (u16*)(ws + 56623104);
  int* gidx = (int*)(ws + 65011712);
  int* cnts = (int*)(ws + 65028096);

  dim3 blk(256);
  prep_k<<<7684, blk, 0, stream>>>(Wq, Wk, Wo, q, k, v, wqb, mask, gidx, cnts);
  proj_k<<<768, blk, 0, stream>>>(qb, kb, vb, wqb, wkb, bq, bk, qp, kp, vtb, gidx, cnts);
  attn_k<<<512, blk, 0, stream>>>(qp, kp, vtb, cnts, ctxb);
  oproj_k<<<dim3(32,16), blk, 0, stream>>>(ctxb, wob, bo, out);
}